// Round 1
// baseline (3519.650 us; speedup 1.0000x reference)
//
#include <hip/hip_runtime.h>
#include <math.h>

#define NND 50000
#define NE  1200000
#define NG  256
#define H   64
#define H2  128
#define H4  256
#define H8  512
#define FIN 5
#define EPS_BN 1e-5f
#define EPS_MSG 1e-7f
#define ENC_NEG_INF 0x007FFFFFu

__device__ __forceinline__ unsigned enc_f(float f) {
    unsigned i = __float_as_uint(f);
    return (i & 0x80000000u) ? ~i : (i | 0x80000000u);
}
__device__ __forceinline__ float dec_f(unsigned u) {
    unsigned i = (u & 0x80000000u) ? (u ^ 0x80000000u) : ~u;
    return __uint_as_float(i);
}

// ---------------- GCNConv stage ----------------

// zero xc slice 0 (strided) and deg
__global__ void k_init_gcn(float* xc, float* deg) {
    int tid = blockIdx.x * blockDim.x + threadIdx.x;
    if (tid >= NND * H) return;
    int n = tid >> 6, c = tid & 63;
    xc[n * H4 + c] = 0.f;
    if (c == 0) deg[n] = 0.f;
}

__global__ void k_conv1(const float* __restrict__ x, const float* __restrict__ W,
                        float* __restrict__ t0) {
    int tid = blockIdx.x * blockDim.x + threadIdx.x;
    if (tid >= NND * H) return;
    int n = tid >> 6, c = tid & 63;
    float acc = 0.f;
#pragma unroll
    for (int k = 0; k < FIN; k++) acc += x[n * FIN + k] * W[k * H + c];
    t0[n * H + c] = acc;
}

__global__ void k_deg(const int* __restrict__ ei, float* deg) {
    int e = blockIdx.x * blockDim.x + threadIdx.x;
    if (e >= NE) return;
    atomicAdd(&deg[ei[NE + e]], 1.f);
}

__global__ void k_dinv(float* deg) {
    int n = blockIdx.x * blockDim.x + threadIdx.x;
    if (n >= NND) return;
    deg[n] = rsqrtf(deg[n] + 1.0f);  // self loop adds 1; deg>=1 always
}

__global__ void k_gcn_edge(const int* __restrict__ ei, const float* __restrict__ t0,
                           const float* __restrict__ dinv, float* xc) {
    int tid = blockIdx.x * blockDim.x + threadIdx.x;
    int e = tid >> 6, c = tid & 63;
    if (e >= NE) return;
    int s = ei[e], d = ei[NE + e];
    atomicAdd(&xc[d * H4 + c], t0[s * H + c] * dinv[s] * dinv[d]);
}

__global__ void k_gcn_final(const float* __restrict__ t0, const float* __restrict__ dinv,
                            const float* __restrict__ cb, const float* __restrict__ bg,
                            const float* __restrict__ bb, float* xc) {
    int tid = blockIdx.x * blockDim.x + threadIdx.x;
    if (tid >= NND * H) return;
    int n = tid >> 6, c = tid & 63;
    float v = xc[n * H4 + c] + t0[n * H + c] * dinv[n] * dinv[n] + cb[c];
    v = v * (bg[c] * rsqrtf(1.f + EPS_BN)) + bb[c];
    xc[n * H4 + c] = fmaxf(v, 0.f);
}

// ---------------- DeepGCN layer ----------------

__global__ void k_ln_prelu(const float* __restrict__ xc, int slice,
                           const float* __restrict__ g, const float* __restrict__ b,
                           const float* __restrict__ a, float* __restrict__ u) {
    int tid = blockIdx.x * blockDim.x + threadIdx.x;
    int n = tid >> 6, c = tid & 63;
    if (n >= NND) return;
    float v = xc[n * H4 + slice * H + c];
    float sum = v, sq = v * v;
#pragma unroll
    for (int off = 32; off >= 1; off >>= 1) {
        sum += __shfl_xor(sum, off, 64);
        sq  += __shfl_xor(sq,  off, 64);
    }
    float mu  = sum * (1.f / H);
    float var = sq * (1.f / H) - mu * mu;
    float y = (v - mu) * rsqrtf(var + EPS_BN) * g[c] + b[c];
    u[n * H + c] = (y >= 0.f) ? y : a[c] * y;
}

__global__ void k_init_gen(unsigned* m, float* s, float* num) {
    int tid = blockIdx.x * blockDim.x + threadIdx.x;
    if (tid >= NND * H) return;
    m[tid] = ENC_NEG_INF;
    s[tid] = 0.f;
    num[tid] = 0.f;
}

__global__ void k_edge_max(const int* __restrict__ ei, const float* __restrict__ u,
                           const float* __restrict__ tptr, int li, unsigned* m) {
    int tid = blockIdx.x * blockDim.x + threadIdx.x;
    int e = tid >> 6, c = tid & 63;
    if (e >= NE) return;
    int s = ei[e], d = ei[NE + e];
    float msg = fmaxf(u[s * H + c], 0.f) + EPS_MSG;
    atomicMax(&m[d * H + c], enc_f(msg * tptr[li]));
}

__global__ void k_edge_sum(const int* __restrict__ ei, const float* __restrict__ u,
                           const float* __restrict__ tptr, int li,
                           const unsigned* __restrict__ m, float* s, float* num) {
    int tid = blockIdx.x * blockDim.x + threadIdx.x;
    int e = tid >> 6, c = tid & 63;
    if (e >= NE) return;
    int sn = ei[e], d = ei[NE + e];
    float msg = fmaxf(u[sn * H + c], 0.f) + EPS_MSG;
    float sc = msg * tptr[li];
    float ex = expf(sc - dec_f(m[d * H + c]));
    atomicAdd(&s[d * H + c], ex);
    atomicAdd(&num[d * H + c], msg * ex);
}

// u := agg + u  (root add); agg = num/s where s>0 else 0
__global__ void k_gen_final(const float* __restrict__ s, const float* __restrict__ num,
                            float* u) {
    int tid = blockIdx.x * blockDim.x + threadIdx.x;
    if (tid >= NND * H) return;
    float sv = s[tid];
    float a = (sv > 0.f) ? (num[tid] / sv) : 0.f;
    u[tid] = u[tid] + a;
}

__global__ void k_mlp1(const float* __restrict__ u, const float* __restrict__ W1,
                       const float* __restrict__ b1, const float* __restrict__ bg,
                       const float* __restrict__ bb, float* __restrict__ z1) {
    int tid = blockIdx.x * blockDim.x + threadIdx.x;
    int n = tid >> 7, j = tid & 127;
    if (n >= NND) return;
    float acc = 0.f;
#pragma unroll
    for (int k = 0; k < H; k++) acc += u[n * H + k] * W1[k * H2 + j];
    acc += b1[j];
    acc = acc * (bg[j] * rsqrtf(1.f + EPS_BN)) + bb[j];
    z1[n * H2 + j] = fmaxf(acc, 0.f);
}

__global__ void k_mlp2(const float* __restrict__ z1, const float* __restrict__ W2,
                       const float* __restrict__ b2, float* xc, int slice) {
    int tid = blockIdx.x * blockDim.x + threadIdx.x;
    int n = tid >> 6, c = tid & 63;
    if (n >= NND) return;
    float acc = 0.f;
#pragma unroll
    for (int k = 0; k < H2; k++) acc += z1[n * H2 + k] * W2[k * H + c];
    acc += b2[c];
    xc[n * H4 + (slice + 1) * H + c] = xc[n * H4 + slice * H + c] + acc;
}

// ---------------- pooling + readout ----------------

__global__ void k_pool_init(float* psum, unsigned* pmax, float* cnt) {
    int tid = blockIdx.x * blockDim.x + threadIdx.x;
    if (tid >= NG * H4) return;
    psum[tid] = 0.f;
    pmax[tid] = ENC_NEG_INF;
    if ((tid & (H4 - 1)) == 0) cnt[tid >> 8] = 0.f;
}

__global__ void k_pool_scatter(const float* __restrict__ xc, const int* __restrict__ batch,
                               float* psum, unsigned* pmax, float* cnt) {
    int tid = blockIdx.x * blockDim.x + threadIdx.x;
    int n = tid >> 8, c = tid & 255;
    if (n >= NND) return;
    int g = batch[n];
    float v = xc[n * H4 + c];
    atomicAdd(&psum[g * H4 + c], v);
    atomicMax(&pmax[g * H4 + c], enc_f(v));
    if (c == 0) atomicAdd(&cnt[g], 1.f);
}

__global__ void k_pool_final(const float* __restrict__ psum, const unsigned* __restrict__ pmax,
                             const float* __restrict__ cnt, float* __restrict__ p0) {
    int tid = blockIdx.x * blockDim.x + threadIdx.x;
    if (tid >= NG * H4) return;
    int g = tid >> 8, c = tid & 255;
    float cc = fmaxf(cnt[g], 1.f);
    p0[g * H8 + c] = psum[g * H4 + c] / cc;
    unsigned e = pmax[g * H4 + c];
    p0[g * H8 + H4 + c] = (e == ENC_NEG_INF) ? 0.f : dec_f(e);
}

__global__ void k_lin1(const float* __restrict__ p0, const float* __restrict__ W,
                       const float* __restrict__ b, float* __restrict__ p1) {
    int tid = blockIdx.x * blockDim.x + threadIdx.x;
    int g = tid >> 7, j = tid & 127;
    if (g >= NG) return;
    float acc = 0.f;
    for (int k = 0; k < H8; k++) acc += p0[g * H8 + k] * W[k * H2 + j];
    p1[g * H2 + j] = fmaxf(acc + b[j], 0.f);
}

__global__ void k_lin2(const float* __restrict__ p1, const float* __restrict__ W,
                       const float* __restrict__ b, float* __restrict__ p2) {
    int tid = blockIdx.x * blockDim.x + threadIdx.x;
    int g = tid >> 6, c = tid & 63;
    if (g >= NG) return;
    float acc = 0.f;
#pragma unroll
    for (int k = 0; k < H2; k++) acc += p1[g * H2 + k] * W[k * H + c];
    p2[g * H + c] = fmaxf(acc + b[c], 0.f);
}

__global__ void k_out(const float* __restrict__ p2, const float* __restrict__ W,
                      const float* __restrict__ b, float* __restrict__ out) {
    int g = blockIdx.x * blockDim.x + threadIdx.x;
    if (g >= NG) return;
    float acc = 0.f;
#pragma unroll
    for (int k = 0; k < H; k++) acc += p2[g * H + k] * W[k];
    out[g] = acc + b[0];
}

extern "C" void kernel_launch(void* const* d_in, const int* in_sizes, int n_in,
                              void* d_out, int out_size, void* d_ws, size_t ws_size,
                              hipStream_t stream) {
    const float* x       = (const float*)d_in[0];
    const int*   ei      = (const int*)d_in[1];
    const int*   batch   = (const int*)d_in[2];
    const float* conv1_W = (const float*)d_in[3];
    const float* conv1_b = (const float*)d_in[4];
    const float* bn1_g   = (const float*)d_in[5];
    const float* bn1_b   = (const float*)d_in[6];
    const float* ln_g    = (const float*)d_in[7];
    const float* ln_b    = (const float*)d_in[8];
    const float* prelu_a = (const float*)d_in[9];
    const float* gen_t   = (const float*)d_in[10];
    const float* mlp_W1  = (const float*)d_in[11];
    const float* mlp_b1  = (const float*)d_in[12];
    const float* mlp_bng = (const float*)d_in[13];
    const float* mlp_bnb = (const float*)d_in[14];
    const float* mlp_W2  = (const float*)d_in[15];
    const float* mlp_b2  = (const float*)d_in[16];
    const float* lin1_W  = (const float*)d_in[17];
    const float* lin1_b  = (const float*)d_in[18];
    const float* lin2_W  = (const float*)d_in[19];
    const float* lin2_b  = (const float*)d_in[20];
    const float* out_W   = (const float*)d_in[21];
    const float* out_b   = (const float*)d_in[22];
    float* out = (float*)d_out;

    // workspace layout (floats)
    float* ws   = (float*)d_ws;
    float* xc   = ws;                    // NND*H4
    float* u    = xc + (size_t)NND * H4; // NND*H
    float* z1   = u + (size_t)NND * H;   // NND*H2 ; aliases: m (uint, first NND*H), s (second NND*H)
    float* num  = z1 + (size_t)NND * H2; // NND*H  ; aliases: t0
    float* psum = num + (size_t)NND * H; // NG*H4
    unsigned* pmax = (unsigned*)(psum + NG * H4); // NG*H4
    float* cnt  = (float*)pmax + NG * H4;         // NG
    float* p0   = cnt + NG;                       // NG*H8
    float* p1   = p0 + NG * H8;                   // NG*H2
    float* p2   = p1 + NG * H2;                   // NG*H

    unsigned* m = (unsigned*)z1;
    float*    s = z1 + (size_t)NND * H;
    float*    t0 = num;
    float*    deg = z1;  // N floats, dead before m is used

    const int B = 256;
    const int gNH  = (NND * H) / B;       // 12500
    const int gNH2 = (NND * H2) / B;      // 25000
    const int gNH4 = (NND * H4) / B;      // 50000
    const int gE   = (NE + B - 1) / B;    // 4688
    const int gEH  = (NE * H) / B;        // 300000
    const int gN   = (NND + B - 1) / B;   // 196

    // ---- GCNConv ----
    k_init_gcn<<<gNH, B, 0, stream>>>(xc, deg);
    k_conv1<<<gNH, B, 0, stream>>>(x, conv1_W, t0);
    k_deg<<<gE, B, 0, stream>>>(ei, deg);
    k_dinv<<<gN, B, 0, stream>>>(deg);
    k_gcn_edge<<<gEH, B, 0, stream>>>(ei, t0, deg, xc);
    k_gcn_final<<<gNH, B, 0, stream>>>(t0, deg, conv1_b, bn1_g, bn1_b, xc);

    // ---- DeepGCN layers ----
    for (int i = 0; i < 3; i++) {
        k_ln_prelu<<<gNH, B, 0, stream>>>(xc, i, ln_g + i * H, ln_b + i * H,
                                          prelu_a + i * H, u);
        k_init_gen<<<gNH, B, 0, stream>>>(m, s, num);
        k_edge_max<<<gEH, B, 0, stream>>>(ei, u, gen_t, i, m);
        k_edge_sum<<<gEH, B, 0, stream>>>(ei, u, gen_t, i, m, s, num);
        k_gen_final<<<gNH, B, 0, stream>>>(s, num, u);
        k_mlp1<<<gNH2, B, 0, stream>>>(u, mlp_W1 + (size_t)i * H * H2, mlp_b1 + i * H2,
                                       mlp_bng + i * H2, mlp_bnb + i * H2, z1);
        k_mlp2<<<gNH, B, 0, stream>>>(z1, mlp_W2 + (size_t)i * H2 * H, mlp_b2 + i * H, xc, i);
    }

    // ---- pooling + readout ----
    k_pool_init<<<(NG * H4) / B, B, 0, stream>>>(psum, pmax, cnt);
    k_pool_scatter<<<gNH4, B, 0, stream>>>(xc, batch, psum, pmax, cnt);
    k_pool_final<<<(NG * H4) / B, B, 0, stream>>>(psum, pmax, cnt, p0);
    k_lin1<<<(NG * H2) / B, B, 0, stream>>>(p0, lin1_W, lin1_b, p1);
    k_lin2<<<(NG * H) / B, B, 0, stream>>>(p1, lin2_W, lin2_b, p2);
    k_out<<<1, NG, 0, stream>>>(p2, out_W, out_b, out);
}

// Round 2
// 1166.763 us; speedup vs baseline: 3.0166x; 3.0166x over previous
//
#include <hip/hip_runtime.h>
#include <math.h>

#define NND 50000
#define NE  1200000
#define NG  256
#define H   64
#define H2  128
#define H4  256
#define H8  512
#define FIN 5
#define EPS_BN 1e-5f
#define EPS_MSG 1e-7f

// ---------------- CSR build (by dst) ----------------

__global__ void k_zero_counts(int* counts) {
    int n = blockIdx.x * blockDim.x + threadIdx.x;
    if (n < NND) counts[n] = 0;
}

__global__ void k_count(const int* __restrict__ ei, int* counts) {
    int e = blockIdx.x * blockDim.x + threadIdx.x;
    if (e >= NE) return;
    atomicAdd(&counts[ei[NE + e]], 1);
}

// single-block exclusive scan: rowptr[0..NND], 1024 threads, wave-shuffle scan
__global__ void k_scan(const int* __restrict__ counts, int* __restrict__ rowptr) {
    __shared__ int wsum[16];
    __shared__ int carry_s;
    int lane = threadIdx.x & 63, wid = threadIdx.x >> 6;
    if (threadIdx.x == 0) { carry_s = 0; rowptr[0] = 0; }
    __syncthreads();
    for (int base = 0; base < NND; base += 1024) {
        int i = base + threadIdx.x;
        int v = (i < NND) ? counts[i] : 0;
        int sv = v;
#pragma unroll
        for (int off = 1; off < 64; off <<= 1) {
            int t = __shfl_up(sv, off, 64);
            if (lane >= off) sv += t;
        }
        if (lane == 63) wsum[wid] = sv;
        __syncthreads();
        if (wid == 0) {
            int w = (lane < 16) ? wsum[lane] : 0;
#pragma unroll
            for (int off = 1; off < 16; off <<= 1) {
                int t = __shfl_up(w, off, 64);
                if (lane >= off) w += t;
            }
            if (lane < 16) wsum[lane] = w;  // inclusive wave sums
        }
        __syncthreads();
        int waveoff = (wid > 0) ? wsum[wid - 1] : 0;
        int inc = carry_s + waveoff + sv;   // inclusive prefix of chunk
        if (i < NND) rowptr[i + 1] = inc;
        __syncthreads();
        if (threadIdx.x == 1023) carry_s += wsum[15];
        __syncthreads();
    }
}

__global__ void k_copy_next(const int* __restrict__ rowptr, int* next) {
    int n = blockIdx.x * blockDim.x + threadIdx.x;
    if (n < NND) next[n] = rowptr[n];
}

__global__ void k_scatter(const int* __restrict__ ei, int* next, int* csr) {
    int e = blockIdx.x * blockDim.x + threadIdx.x;
    if (e >= NE) return;
    int d = ei[NE + e];
    int pos = atomicAdd(&next[d], 1);
    csr[pos] = ei[e];
}

__global__ void k_dinv(const int* __restrict__ rowptr, float* dinv) {
    int n = blockIdx.x * blockDim.x + threadIdx.x;
    if (n >= NND) return;
    dinv[n] = rsqrtf((float)(rowptr[n + 1] - rowptr[n]) + 1.0f);  // +1 self loop
}

// ---------------- GCNConv (fused gather) ----------------

__global__ void k_conv1(const float* __restrict__ x, const float* __restrict__ W,
                        float* __restrict__ t0) {
    int tid = blockIdx.x * blockDim.x + threadIdx.x;
    if (tid >= NND * H) return;
    int n = tid >> 6, c = tid & 63;
    float acc = 0.f;
#pragma unroll
    for (int k = 0; k < FIN; k++) acc += x[n * FIN + k] * W[k * H + c];
    t0[n * H + c] = acc;
}

__global__ void k_gcn(const int* __restrict__ rowptr, const int* __restrict__ csr,
                      const float* __restrict__ t0, const float* __restrict__ dinv,
                      const float* __restrict__ cb, const float* __restrict__ bg,
                      const float* __restrict__ bb, float* __restrict__ xc) {
    int d = (blockIdx.x * blockDim.x + threadIdx.x) >> 6;
    int lane = threadIdx.x & 63;
    if (d >= NND) return;
    int beg = rowptr[d], end = rowptr[d + 1];
    float acc = 0.f;
    int i = beg;
    for (; i + 4 <= end; i += 4) {
        int s0 = csr[i], s1 = csr[i + 1], s2 = csr[i + 2], s3 = csr[i + 3];
        float v0 = t0[s0 * H + lane] * dinv[s0];
        float v1 = t0[s1 * H + lane] * dinv[s1];
        float v2 = t0[s2 * H + lane] * dinv[s2];
        float v3 = t0[s3 * H + lane] * dinv[s3];
        acc += (v0 + v1) + (v2 + v3);
    }
    for (; i < end; i++) { int s = csr[i]; acc += t0[s * H + lane] * dinv[s]; }
    float dd = dinv[d];
    float v = acc * dd + t0[d * H + lane] * dd * dd + cb[lane];
    v = v * (bg[lane] * rsqrtf(1.f + EPS_BN)) + bb[lane];
    xc[(size_t)d * H4 + lane] = fmaxf(v, 0.f);
}

// ---------------- DeepGCN layer ----------------

__global__ void k_ln_prelu(const float* __restrict__ xc, int slice,
                           const float* __restrict__ g, const float* __restrict__ b,
                           const float* __restrict__ a, float* __restrict__ u) {
    int tid = blockIdx.x * blockDim.x + threadIdx.x;
    int n = tid >> 6, c = tid & 63;
    if (n >= NND) return;
    float v = xc[(size_t)n * H4 + slice * H + c];
    float sum = v, sq = v * v;
#pragma unroll
    for (int off = 32; off >= 1; off >>= 1) {
        sum += __shfl_xor(sum, off, 64);
        sq  += __shfl_xor(sq,  off, 64);
    }
    float mu  = sum * (1.f / H);
    float var = sq * (1.f / H) - mu * mu;
    float y = (v - mu) * rsqrtf(var + EPS_BN) * g[c] + b[c];
    u[n * H + c] = (y >= 0.f) ? y : a[c] * y;
}

// GENConv softmax aggregation, one wave per dst node, constant-shift exp
// (LN-bounded inputs: |sc| <= ~8, so exp(sc-8) never overflows; the constant
//  shift cancels exactly in num/s — no segment-max pass needed)
__global__ void k_gen(const int* __restrict__ rowptr, const int* __restrict__ csr,
                      const float* __restrict__ u, const float* __restrict__ tptr,
                      int li, float* __restrict__ ua) {
    int d = (blockIdx.x * blockDim.x + threadIdx.x) >> 6;
    int lane = threadIdx.x & 63;
    if (d >= NND) return;
    float t = tptr[li];
    int beg = rowptr[d], end = rowptr[d + 1];
    float s = 0.f, num = 0.f;
    int i = beg;
    for (; i + 4 <= end; i += 4) {
        int s0 = csr[i], s1 = csr[i + 1], s2 = csr[i + 2], s3 = csr[i + 3];
        float m0 = fmaxf(u[s0 * H + lane], 0.f) + EPS_MSG;
        float m1 = fmaxf(u[s1 * H + lane], 0.f) + EPS_MSG;
        float m2 = fmaxf(u[s2 * H + lane], 0.f) + EPS_MSG;
        float m3 = fmaxf(u[s3 * H + lane], 0.f) + EPS_MSG;
        float e0 = __expf(m0 * t - 8.f);
        float e1 = __expf(m1 * t - 8.f);
        float e2 = __expf(m2 * t - 8.f);
        float e3 = __expf(m3 * t - 8.f);
        s   += (e0 + e1) + (e2 + e3);
        num += (m0 * e0 + m1 * e1) + (m2 * e2 + m3 * e3);
    }
    for (; i < end; i++) {
        int sn = csr[i];
        float mm = fmaxf(u[sn * H + lane], 0.f) + EPS_MSG;
        float ee = __expf(mm * t - 8.f);
        s += ee; num += mm * ee;
    }
    float agg = (s > 0.f) ? num / s : 0.f;
    ua[d * H + lane] = u[d * H + lane] + agg;
}

__global__ void k_mlp1(const float* __restrict__ u, const float* __restrict__ W1,
                       const float* __restrict__ b1, const float* __restrict__ bg,
                       const float* __restrict__ bb, float* __restrict__ z1) {
    int tid = blockIdx.x * blockDim.x + threadIdx.x;
    int n = tid >> 7, j = tid & 127;
    if (n >= NND) return;
    float acc = 0.f;
#pragma unroll
    for (int k = 0; k < H; k++) acc += u[n * H + k] * W1[k * H2 + j];
    acc += b1[j];
    acc = acc * (bg[j] * rsqrtf(1.f + EPS_BN)) + bb[j];
    z1[n * H2 + j] = fmaxf(acc, 0.f);
}

__global__ void k_mlp2(const float* __restrict__ z1, const float* __restrict__ W2,
                       const float* __restrict__ b2, float* xc, int slice) {
    int tid = blockIdx.x * blockDim.x + threadIdx.x;
    int n = tid >> 6, c = tid & 63;
    if (n >= NND) return;
    float acc = 0.f;
#pragma unroll
    for (int k = 0; k < H2; k++) acc += z1[n * H2 + k] * W2[k * H + c];
    acc += b2[c];
    xc[(size_t)n * H4 + (slice + 1) * H + c] = xc[(size_t)n * H4 + slice * H + c] + acc;
}

// ---------------- pooling + readout ----------------

// batch_idx is sorted: one block per graph, binary-search the node range
__global__ void k_pool(const float* __restrict__ xc, const int* __restrict__ batch,
                       float* __restrict__ p0) {
    int g = blockIdx.x;
    int c = threadIdx.x;  // 256 channels
    int lo = 0, hi = NND;
    while (lo < hi) { int mid = (lo + hi) >> 1; if (batch[mid] < g) lo = mid + 1; else hi = mid; }
    int start = lo;
    hi = NND;
    while (lo < hi) { int mid = (lo + hi) >> 1; if (batch[mid] < g + 1) lo = mid + 1; else hi = mid; }
    int end = lo;
    float sum = 0.f, mx = -INFINITY;
    for (int n = start; n < end; n++) {
        float v = xc[(size_t)n * H4 + c];
        sum += v;
        mx = fmaxf(mx, v);
    }
    int cnt = end - start;
    p0[g * H8 + c] = sum / fmaxf((float)cnt, 1.f);
    p0[g * H8 + H4 + c] = (cnt > 0) ? mx : 0.f;
}

__global__ void k_lin1(const float* __restrict__ p0, const float* __restrict__ W,
                       const float* __restrict__ b, float* __restrict__ p1) {
    int tid = blockIdx.x * blockDim.x + threadIdx.x;
    int g = tid >> 7, j = tid & 127;
    if (g >= NG) return;
    float acc = 0.f;
    for (int k = 0; k < H8; k++) acc += p0[g * H8 + k] * W[k * H2 + j];
    p1[g * H2 + j] = fmaxf(acc + b[j], 0.f);
}

__global__ void k_lin2(const float* __restrict__ p1, const float* __restrict__ W,
                       const float* __restrict__ b, float* __restrict__ p2) {
    int tid = blockIdx.x * blockDim.x + threadIdx.x;
    int g = tid >> 6, c = tid & 63;
    if (g >= NG) return;
    float acc = 0.f;
#pragma unroll
    for (int k = 0; k < H2; k++) acc += p1[g * H2 + k] * W[k * H + c];
    p2[g * H + c] = fmaxf(acc + b[c], 0.f);
}

__global__ void k_out(const float* __restrict__ p2, const float* __restrict__ W,
                      const float* __restrict__ b, float* __restrict__ out) {
    int g = blockIdx.x * blockDim.x + threadIdx.x;
    if (g >= NG) return;
    float acc = 0.f;
#pragma unroll
    for (int k = 0; k < H; k++) acc += p2[g * H + k] * W[k];
    out[g] = acc + b[0];
}

extern "C" void kernel_launch(void* const* d_in, const int* in_sizes, int n_in,
                              void* d_out, int out_size, void* d_ws, size_t ws_size,
                              hipStream_t stream) {
    const float* x       = (const float*)d_in[0];
    const int*   ei      = (const int*)d_in[1];
    const int*   batch   = (const int*)d_in[2];
    const float* conv1_W = (const float*)d_in[3];
    const float* conv1_b = (const float*)d_in[4];
    const float* bn1_g   = (const float*)d_in[5];
    const float* bn1_b   = (const float*)d_in[6];
    const float* ln_g    = (const float*)d_in[7];
    const float* ln_b    = (const float*)d_in[8];
    const float* prelu_a = (const float*)d_in[9];
    const float* gen_t   = (const float*)d_in[10];
    const float* mlp_W1  = (const float*)d_in[11];
    const float* mlp_b1  = (const float*)d_in[12];
    const float* mlp_bng = (const float*)d_in[13];
    const float* mlp_bnb = (const float*)d_in[14];
    const float* mlp_W2  = (const float*)d_in[15];
    const float* mlp_b2  = (const float*)d_in[16];
    const float* lin1_W  = (const float*)d_in[17];
    const float* lin1_b  = (const float*)d_in[18];
    const float* lin2_W  = (const float*)d_in[19];
    const float* lin2_b  = (const float*)d_in[20];
    const float* out_W   = (const float*)d_in[21];
    const float* out_b   = (const float*)d_in[22];
    float* out = (float*)d_out;

    // workspace layout
    float* ws   = (float*)d_ws;
    float* xc   = ws;                          // NND*H4 = 12.8M floats
    float* A    = xc + (size_t)NND * H4;       // 6.4M floats: u = A[0:3.2M], z1 = A (u dead when z1 written)
    float* u    = A;
    float* z1   = A;
    float* ua   = A + (size_t)NND * H2;        // 3.2M floats (t0 aliases; GCN stage only)
    float* t0   = ua;
    float* dinv = ua + (size_t)NND * H;        // 50000
    int* rowptr = (int*)(dinv + NND);          // NND+1
    int* next   = rowptr + (NND + 1);          // NND
    int* counts = next + NND;                  // NND
    int* csr    = counts + NND;                // NE
    float* p0   = (float*)(csr + NE);          // NG*H8
    float* p1   = p0 + NG * H8;                // NG*H2
    float* p2   = p1 + NG * H2;                // NG*H

    const int B = 256;
    const int gN   = (NND + B - 1) / B;    // 196
    const int gE   = (NE + B - 1) / B;     // 4688
    const int gNH  = (NND * H) / B;        // 12500
    const int gNH2 = (NND * H2) / B;       // 25000

    // ---- CSR build ----
    k_zero_counts<<<gN, B, 0, stream>>>(counts);
    k_count<<<gE, B, 0, stream>>>(ei, counts);
    k_scan<<<1, 1024, 0, stream>>>(counts, rowptr);
    k_copy_next<<<gN, B, 0, stream>>>(rowptr, next);
    k_scatter<<<gE, B, 0, stream>>>(ei, next, csr);
    k_dinv<<<gN, B, 0, stream>>>(rowptr, dinv);

    // ---- GCNConv ----
    k_conv1<<<gNH, B, 0, stream>>>(x, conv1_W, t0);
    k_gcn<<<gNH, B, 0, stream>>>(rowptr, csr, t0, dinv, conv1_b, bn1_g, bn1_b, xc);

    // ---- DeepGCN layers ----
    for (int i = 0; i < 3; i++) {
        k_ln_prelu<<<gNH, B, 0, stream>>>(xc, i, ln_g + i * H, ln_b + i * H,
                                          prelu_a + i * H, u);
        k_gen<<<gNH, B, 0, stream>>>(rowptr, csr, u, gen_t, i, ua);
        k_mlp1<<<gNH2, B, 0, stream>>>(ua, mlp_W1 + (size_t)i * H * H2, mlp_b1 + i * H2,
                                       mlp_bng + i * H2, mlp_bnb + i * H2, z1);
        k_mlp2<<<gNH, B, 0, stream>>>(z1, mlp_W2 + (size_t)i * H2 * H, mlp_b2 + i * H, xc, i);
    }

    // ---- pooling + readout ----
    k_pool<<<NG, H4, 0, stream>>>(xc, batch, p0);
    k_lin1<<<(NG * H2) / B, B, 0, stream>>>(p0, lin1_W, lin1_b, p1);
    k_lin2<<<(NG * H) / B, B, 0, stream>>>(p1, lin2_W, lin2_b, p2);
    k_out<<<1, NG, 0, stream>>>(p2, out_W, out_b, out);
}

// Round 3
// 703.457 us; speedup vs baseline: 5.0034x; 1.6586x over previous
//
#include <hip/hip_runtime.h>
#include <math.h>

#define NND 50000
#define NE  1200000
#define NG  256
#define H   64
#define H2  128
#define H4  256
#define H8  512
#define FIN 5
#define EPS_BN 1e-5f
#define EPS_MSG 1e-7f
#define NB 196          // ceil(NND/256)

// ---------------- CSR build (by dst) ----------------

__global__ void k_zero_counts(int* counts) {
    int n = blockIdx.x * blockDim.x + threadIdx.x;
    if (n < NND) counts[n] = 0;
}

__global__ void k_count(const int* __restrict__ ei, int* counts) {
    int e = blockIdx.x * blockDim.x + threadIdx.x;
    if (e >= NE) return;
    atomicAdd(&counts[ei[NE + e]], 1);
}

// hierarchical scan: per-block inclusive + block sums
__global__ void k_scan1(const int* __restrict__ counts, int* __restrict__ rowptr,
                        int* __restrict__ bsum) {
    __shared__ int wsum[4];
    int b = blockIdx.x, t = threadIdx.x;
    int i = b * 256 + t;
    int v = (i < NND) ? counts[i] : 0;
    int lane = t & 63, wid = t >> 6;
    int sv = v;
#pragma unroll
    for (int off = 1; off < 64; off <<= 1) {
        int x = __shfl_up(sv, off, 64);
        if (lane >= off) sv += x;
    }
    if (lane == 63) wsum[wid] = sv;
    __syncthreads();
    int woff = 0;
    for (int w = 0; w < wid; w++) woff += wsum[w];
    int inc = woff + sv;
    if (i < NND) rowptr[i + 1] = inc;  // within-block inclusive (offset added later)
    if (t == 255) bsum[b] = inc;
    __syncthreads();
}

__global__ void k_scan2(const int* __restrict__ bsum, int* __restrict__ boff,
                        int* __restrict__ rowptr) {
    __shared__ int wsum[4];
    int t = threadIdx.x;
    int v = (t < NB) ? bsum[t] : 0;
    int lane = t & 63, wid = t >> 6;
    int sv = v;
#pragma unroll
    for (int off = 1; off < 64; off <<= 1) {
        int x = __shfl_up(sv, off, 64);
        if (lane >= off) sv += x;
    }
    if (lane == 63) wsum[wid] = sv;
    __syncthreads();
    int woff = 0;
    for (int w = 0; w < wid; w++) woff += wsum[w];
    if (t < NB) boff[t] = woff + sv - v;  // exclusive block offset
    if (t == 0) rowptr[0] = 0;
}

__global__ void k_scan3(const int* __restrict__ boff, const int* __restrict__ counts,
                        int* __restrict__ rowptr, int* __restrict__ next) {
    int i = blockIdx.x * 256 + threadIdx.x;
    if (i >= NND) return;
    int r = rowptr[i + 1] + boff[i >> 8];
    rowptr[i + 1] = r;
    next[i] = r - counts[i];  // exclusive prefix = fill cursor
}

__global__ void k_scatter(const int* __restrict__ ei, int* next, int* csr) {
    int e = blockIdx.x * blockDim.x + threadIdx.x;
    if (e >= NE) return;
    int d = ei[NE + e];
    int pos = atomicAdd(&next[d], 1);
    csr[pos] = ei[e];
}

__global__ void k_dinv(const int* __restrict__ counts, float* dinv) {
    int n = blockIdx.x * blockDim.x + threadIdx.x;
    if (n >= NND) return;
    dinv[n] = rsqrtf((float)counts[n] + 1.0f);  // +1 self loop
}

// ---------------- GCNConv (fused gather + BN + ReLU + LN0 + PReLU0) ----------------

__global__ void k_conv1(const float* __restrict__ x, const float* __restrict__ W,
                        float* __restrict__ t0) {
    int tid = blockIdx.x * blockDim.x + threadIdx.x;
    if (tid >= NND * H) return;
    int n = tid >> 6, c = tid & 63;
    float acc = 0.f;
#pragma unroll
    for (int k = 0; k < FIN; k++) acc += x[n * FIN + k] * W[k * H + c];
    t0[n * H + c] = acc;
}

__global__ void k_gcn(const int* __restrict__ rowptr, const int* __restrict__ csr,
                      const float* __restrict__ t0, const float* __restrict__ dinv,
                      const float* __restrict__ cb, const float* __restrict__ bg,
                      const float* __restrict__ bb,
                      const float* __restrict__ lg, const float* __restrict__ lb,
                      const float* __restrict__ pa,
                      float* __restrict__ xc, float* __restrict__ u) {
    int d = (blockIdx.x * blockDim.x + threadIdx.x) >> 6;
    int lane = threadIdx.x & 63;
    if (d >= NND) return;
    int beg = rowptr[d], end = rowptr[d + 1];
    float acc = 0.f;
    int i = beg;
    for (; i + 4 <= end; i += 4) {
        int s0 = csr[i], s1 = csr[i + 1], s2 = csr[i + 2], s3 = csr[i + 3];
        float v0 = t0[s0 * H + lane] * dinv[s0];
        float v1 = t0[s1 * H + lane] * dinv[s1];
        float v2 = t0[s2 * H + lane] * dinv[s2];
        float v3 = t0[s3 * H + lane] * dinv[s3];
        acc += (v0 + v1) + (v2 + v3);
    }
    for (; i < end; i++) { int s = csr[i]; acc += t0[s * H + lane] * dinv[s]; }
    float dd = dinv[d];
    float v = acc * dd + t0[d * H + lane] * dd * dd + cb[lane];
    v = v * (bg[lane] * rsqrtf(1.f + EPS_BN)) + bb[lane];
    float x0 = fmaxf(v, 0.f);
    xc[(size_t)d * H4 + lane] = x0;
    // fused LayerNorm(layer 0) + PReLU
    float sum = x0, sq = x0 * x0;
#pragma unroll
    for (int off = 32; off >= 1; off >>= 1) {
        sum += __shfl_xor(sum, off, 64);
        sq  += __shfl_xor(sq,  off, 64);
    }
    float mu  = sum * (1.f / H);
    float var = sq * (1.f / H) - mu * mu;
    float y = (x0 - mu) * rsqrtf(var + EPS_BN) * lg[lane] + lb[lane];
    u[d * H + lane] = (y >= 0.f) ? y : pa[lane] * y;
}

// ---------------- GENConv softmax aggregation (gather) ----------------

__global__ void k_gen(const int* __restrict__ rowptr, const int* __restrict__ csr,
                      const float* __restrict__ u, const float* __restrict__ tptr,
                      int li, float* __restrict__ ua) {
    int d = (blockIdx.x * blockDim.x + threadIdx.x) >> 6;
    int lane = threadIdx.x & 63;
    if (d >= NND) return;
    float t = tptr[li];
    int beg = rowptr[d], end = rowptr[d + 1];
    float s = 0.f, num = 0.f;
    int i = beg;
    for (; i + 4 <= end; i += 4) {
        int s0 = csr[i], s1 = csr[i + 1], s2 = csr[i + 2], s3 = csr[i + 3];
        float m0 = fmaxf(u[s0 * H + lane], 0.f) + EPS_MSG;
        float m1 = fmaxf(u[s1 * H + lane], 0.f) + EPS_MSG;
        float m2 = fmaxf(u[s2 * H + lane], 0.f) + EPS_MSG;
        float m3 = fmaxf(u[s3 * H + lane], 0.f) + EPS_MSG;
        float e0 = __expf(m0 * t - 8.f);
        float e1 = __expf(m1 * t - 8.f);
        float e2 = __expf(m2 * t - 8.f);
        float e3 = __expf(m3 * t - 8.f);
        s   += (e0 + e1) + (e2 + e3);
        num += (m0 * e0 + m1 * e1) + (m2 * e2 + m3 * e3);
    }
    for (; i < end; i++) {
        int sn = csr[i];
        float mm = fmaxf(u[sn * H + lane], 0.f) + EPS_MSG;
        float ee = __expf(mm * t - 8.f);
        s += ee; num += mm * ee;
    }
    float agg = (s > 0.f) ? num / s : 0.f;
    ua[d * H + lane] = u[d * H + lane] + agg;
}

// ---------------- fused MLP: z1=relu(BN(ua@W1+b1)); z2=z1@W2+b2;
//                  xc[i+1]=xc[i]+z2; optionally u_next=prelu(LN(xc[i+1])) ----

__global__ void __launch_bounds__(256)
k_mlp(const float* __restrict__ ua,
      const float* __restrict__ W1, const float* __restrict__ b1,
      const float* __restrict__ bng, const float* __restrict__ bnb,
      const float* __restrict__ W2, const float* __restrict__ b2,
      float* __restrict__ xc, int slice,
      const float* __restrict__ lg, const float* __restrict__ lb,
      const float* __restrict__ pa, float* __restrict__ u_next, int do_ln) {
    __shared__ __align__(16) float u_t[64][36];    // [k][node], padded
    __shared__ __align__(16) float z1_t[128][36];  // [j][node], padded
    int t = threadIdx.x;
    int nb = blockIdx.x * 32;

    // stage ua tile, transposed
#pragma unroll
    for (int r = 0; r < 8; r++) {
        int flat = t + 256 * r;          // 0..2047
        int n = flat >> 6, c = flat & 63;
        int gn = nb + n;
        u_t[c][n] = (gn < NND) ? ua[gn * H + c] : 0.f;
    }
    __syncthreads();

    // phase 1: z1[n][j] for 32 nodes x 128 j
    {
        int j = t & 127;
        int grp = t >> 7;      // 0/1 -> nodes [16*grp, 16*grp+16)
        int n0 = grp * 16;
        float acc[16];
#pragma unroll
        for (int m = 0; m < 16; m++) acc[m] = 0.f;
        for (int k = 0; k < 64; k++) {
            float w = W1[k * H2 + j];
            const float4* up = (const float4*)&u_t[k][n0];
            float4 a0 = up[0], a1 = up[1], a2 = up[2], a3 = up[3];
            acc[0]  += a0.x * w; acc[1]  += a0.y * w; acc[2]  += a0.z * w; acc[3]  += a0.w * w;
            acc[4]  += a1.x * w; acc[5]  += a1.y * w; acc[6]  += a1.z * w; acc[7]  += a1.w * w;
            acc[8]  += a2.x * w; acc[9]  += a2.y * w; acc[10] += a2.z * w; acc[11] += a2.w * w;
            acc[12] += a3.x * w; acc[13] += a3.y * w; acc[14] += a3.z * w; acc[15] += a3.w * w;
        }
        float b1v = b1[j];
        float bs = bng[j] * rsqrtf(1.f + EPS_BN);
        float bbv = bnb[j];
        float* zr = &z1_t[j][n0];
#pragma unroll
        for (int m = 0; m < 16; m++)
            zr[m] = fmaxf((acc[m] + b1v) * bs + bbv, 0.f);
    }
    __syncthreads();

    // phase 2: z2[n][c] for 32 nodes x 64 c; wave w handles nodes [8w, 8w+8)
    {
        int c = t & 63;
        int g2 = t >> 6;       // wave id 0..3
        int m0 = g2 * 8;
        float acc[8];
#pragma unroll
        for (int m = 0; m < 8; m++) acc[m] = 0.f;
        for (int j = 0; j < 128; j++) {
            float w = W2[j * H + c];
            const float4* zp = (const float4*)&z1_t[j][m0];
            float4 z0 = zp[0], z1v = zp[1];
            acc[0] += z0.x * w;  acc[1] += z0.y * w;
            acc[2] += z0.z * w;  acc[3] += z0.w * w;
            acc[4] += z1v.x * w; acc[5] += z1v.y * w;
            acc[6] += z1v.z * w; acc[7] += z1v.w * w;
        }
        float b2v = b2[c];
        float lgv = 0.f, lbv = 0.f, pav = 0.f;
        if (do_ln) { lgv = lg[c]; lbv = lb[c]; pav = pa[c]; }
#pragma unroll
        for (int q = 0; q < 8; q++) {
            int gn = nb + m0 + q;
            float v = 0.f;
            if (gn < NND) {
                v = xc[(size_t)gn * H4 + slice * H + c] + acc[q] + b2v;
                xc[(size_t)gn * H4 + (slice + 1) * H + c] = v;
            }
            if (do_ln) {
                float sum = v, sq = v * v;
#pragma unroll
                for (int off = 32; off >= 1; off >>= 1) {
                    sum += __shfl_xor(sum, off, 64);
                    sq  += __shfl_xor(sq,  off, 64);
                }
                float mu  = sum * (1.f / H);
                float var = sq * (1.f / H) - mu * mu;
                float y = (v - mu) * rsqrtf(var + EPS_BN) * lgv + lbv;
                if (gn < NND) u_next[gn * H + c] = (y >= 0.f) ? y : pav * y;
            }
        }
    }
}

// ---------------- pooling + readout ----------------

__global__ void k_pool(const float* __restrict__ xc, const int* __restrict__ batch,
                       float* __restrict__ p0) {
    int g = blockIdx.x;
    int c = threadIdx.x;  // 256 channels
    int lo = 0, hi = NND;
    while (lo < hi) { int mid = (lo + hi) >> 1; if (batch[mid] < g) lo = mid + 1; else hi = mid; }
    int start = lo;
    hi = NND;
    while (lo < hi) { int mid = (lo + hi) >> 1; if (batch[mid] < g + 1) lo = mid + 1; else hi = mid; }
    int end = lo;
    float sum = 0.f, mx = -INFINITY;
    for (int n = start; n < end; n++) {
        float v = xc[(size_t)n * H4 + c];
        sum += v;
        mx = fmaxf(mx, v);
    }
    int cnt = end - start;
    p0[g * H8 + c] = sum / fmaxf((float)cnt, 1.f);
    p0[g * H8 + H4 + c] = (cnt > 0) ? mx : 0.f;
}

__global__ void k_lin1(const float* __restrict__ p0, const float* __restrict__ W,
                       const float* __restrict__ b, float* __restrict__ p1) {
    int tid = blockIdx.x * blockDim.x + threadIdx.x;
    int g = tid >> 7, j = tid & 127;
    if (g >= NG) return;
    float acc = 0.f;
    for (int k = 0; k < H8; k++) acc += p0[g * H8 + k] * W[k * H2 + j];
    p1[g * H2 + j] = fmaxf(acc + b[j], 0.f);
}

__global__ void k_lin2(const float* __restrict__ p1, const float* __restrict__ W,
                       const float* __restrict__ b, float* __restrict__ p2) {
    int tid = blockIdx.x * blockDim.x + threadIdx.x;
    int g = tid >> 6, c = tid & 63;
    if (g >= NG) return;
    float acc = 0.f;
#pragma unroll
    for (int k = 0; k < H2; k++) acc += p1[g * H2 + k] * W[k * H + c];
    p2[g * H + c] = fmaxf(acc + b[c], 0.f);
}

__global__ void k_out(const float* __restrict__ p2, const float* __restrict__ W,
                      const float* __restrict__ b, float* __restrict__ out) {
    int g = blockIdx.x * blockDim.x + threadIdx.x;
    if (g >= NG) return;
    float acc = 0.f;
#pragma unroll
    for (int k = 0; k < H; k++) acc += p2[g * H + k] * W[k];
    out[g] = acc + b[0];
}

extern "C" void kernel_launch(void* const* d_in, const int* in_sizes, int n_in,
                              void* d_out, int out_size, void* d_ws, size_t ws_size,
                              hipStream_t stream) {
    const float* x       = (const float*)d_in[0];
    const int*   ei      = (const int*)d_in[1];
    const int*   batch   = (const int*)d_in[2];
    const float* conv1_W = (const float*)d_in[3];
    const float* conv1_b = (const float*)d_in[4];
    const float* bn1_g   = (const float*)d_in[5];
    const float* bn1_b   = (const float*)d_in[6];
    const float* ln_g    = (const float*)d_in[7];
    const float* ln_b    = (const float*)d_in[8];
    const float* prelu_a = (const float*)d_in[9];
    const float* gen_t   = (const float*)d_in[10];
    const float* mlp_W1  = (const float*)d_in[11];
    const float* mlp_b1  = (const float*)d_in[12];
    const float* mlp_bng = (const float*)d_in[13];
    const float* mlp_bnb = (const float*)d_in[14];
    const float* mlp_W2  = (const float*)d_in[15];
    const float* mlp_b2  = (const float*)d_in[16];
    const float* lin1_W  = (const float*)d_in[17];
    const float* lin1_b  = (const float*)d_in[18];
    const float* lin2_W  = (const float*)d_in[19];
    const float* lin2_b  = (const float*)d_in[20];
    const float* out_W   = (const float*)d_in[21];
    const float* out_b   = (const float*)d_in[22];
    float* out = (float*)d_out;

    // workspace layout
    float* ws   = (float*)d_ws;
    float* xc   = ws;                          // NND*H4
    float* u    = xc + (size_t)NND * H4;       // NND*H (LN output; reused as u_next)
    float* ua   = u + (size_t)NND * H;         // NND*H (gen output; t0 aliases)
    float* t0   = ua;
    float* dinv = ua + (size_t)NND * H;        // NND
    int* rowptr = (int*)(dinv + NND);          // NND+1
    int* next   = rowptr + (NND + 1);          // NND
    int* counts = next + NND;                  // NND
    int* bsum   = counts + NND;                // NB
    int* boff   = bsum + NB;                   // NB
    int* csr    = boff + NB;                   // NE
    float* p0   = (float*)(csr + NE);          // NG*H8
    float* p1   = p0 + NG * H8;                // NG*H2
    float* p2   = p1 + NG * H2;                // NG*H

    const int B = 256;
    const int gN   = (NND + B - 1) / B;    // 196
    const int gE   = (NE + B - 1) / B;     // 4688
    const int gNH  = (NND * H) / B;        // 12500
    const int gMLP = (NND + 31) / 32;      // 1563

    // ---- CSR build ----
    k_zero_counts<<<gN, B, 0, stream>>>(counts);
    k_count<<<gE, B, 0, stream>>>(ei, counts);
    k_scan1<<<NB, B, 0, stream>>>(counts, rowptr, bsum);
    k_scan2<<<1, B, 0, stream>>>(bsum, boff, rowptr);
    k_scan3<<<NB, B, 0, stream>>>(boff, counts, rowptr, next);
    k_scatter<<<gE, B, 0, stream>>>(ei, next, csr);
    k_dinv<<<gN, B, 0, stream>>>(counts, dinv);

    // ---- GCNConv + LN0/PReLU0 ----
    k_conv1<<<gNH, B, 0, stream>>>(x, conv1_W, t0);
    k_gcn<<<gNH, B, 0, stream>>>(rowptr, csr, t0, dinv, conv1_b, bn1_g, bn1_b,
                                 ln_g, ln_b, prelu_a, xc, u);

    // ---- DeepGCN layers ----
    for (int i = 0; i < 3; i++) {
        k_gen<<<gNH, B, 0, stream>>>(rowptr, csr, u, gen_t, i, ua);
        int do_ln = (i < 2) ? 1 : 0;
        k_mlp<<<gMLP, B, 0, stream>>>(ua,
                                      mlp_W1 + (size_t)i * H * H2, mlp_b1 + i * H2,
                                      mlp_bng + i * H2, mlp_bnb + i * H2,
                                      mlp_W2 + (size_t)i * H2 * H, mlp_b2 + i * H,
                                      xc, i,
                                      ln_g + (i + 1) * H, ln_b + (i + 1) * H,
                                      prelu_a + (i + 1) * H, u, do_ln);
    }

    // ---- pooling + readout ----
    k_pool<<<NG, H4, 0, stream>>>(xc, batch, p0);
    k_lin1<<<(NG * H2) / B, B, 0, stream>>>(p0, lin1_W, lin1_b, p1);
    k_lin2<<<(NG * H) / B, B, 0, stream>>>(p1, lin2_W, lin2_b, p2);
    k_out<<<1, NG, 0, stream>>>(p2, out_W, out_b, out);
}

// Round 4
// 627.229 us; speedup vs baseline: 5.6114x; 1.1215x over previous
//
#include <hip/hip_runtime.h>
#include <math.h>

#define NND 50000
#define NE  1200000
#define NG  256
#define H   64
#define H2  128
#define H4  256
#define H8  512
#define FIN 5
#define EPS_BN 1e-5f
#define EPS_MSG 1e-7f
#define NB 196          // ceil(NND/256)
#define NXP 8           // XCD partitions
#define DPART 6250      // NND / NXP
#define ECH 4688        // ceil(NE/256)

// ---------------- CSR build (by dst), XCD-partitioned ----------------

__global__ void k_zero_counts(int* counts) {
    int n = blockIdx.x * blockDim.x + threadIdx.x;
    if (n < NND) counts[n] = 0;
}

// grid = NXP * ECH; block b: partition g=b&7, edge chunk b>>3.
// With round-robin blockIdx->XCD mapping, partition g's counters stay in one
// XCD's L2 (correct regardless of mapping; locality is the heuristic).
__global__ void k_count_p(const int* __restrict__ ei, int* counts) {
    int b = blockIdx.x;
    int g = b & (NXP - 1);
    int e = (b >> 3) * 256 + threadIdx.x;
    if (e >= NE) return;
    int d = ei[NE + e];
    if ((unsigned)(d - g * DPART) < (unsigned)DPART) atomicAdd(&counts[d], 1);
}

__global__ void k_scan1(const int* __restrict__ counts, int* __restrict__ rowptr,
                        int* __restrict__ bsum) {
    __shared__ int wsum[4];
    int b = blockIdx.x, t = threadIdx.x;
    int i = b * 256 + t;
    int v = (i < NND) ? counts[i] : 0;
    int lane = t & 63, wid = t >> 6;
    int sv = v;
#pragma unroll
    for (int off = 1; off < 64; off <<= 1) {
        int x = __shfl_up(sv, off, 64);
        if (lane >= off) sv += x;
    }
    if (lane == 63) wsum[wid] = sv;
    __syncthreads();
    int woff = 0;
    for (int w = 0; w < wid; w++) woff += wsum[w];
    int inc = woff + sv;
    if (i < NND) rowptr[i + 1] = inc;
    if (t == 255) bsum[b] = inc;
}

__global__ void k_scan2(const int* __restrict__ bsum, int* __restrict__ boff,
                        int* __restrict__ rowptr) {
    __shared__ int wsum[4];
    int t = threadIdx.x;
    int v = (t < NB) ? bsum[t] : 0;
    int lane = t & 63, wid = t >> 6;
    int sv = v;
#pragma unroll
    for (int off = 1; off < 64; off <<= 1) {
        int x = __shfl_up(sv, off, 64);
        if (lane >= off) sv += x;
    }
    if (lane == 63) wsum[wid] = sv;
    __syncthreads();
    int woff = 0;
    for (int w = 0; w < wid; w++) woff += wsum[w];
    if (t < NB) boff[t] = woff + sv - v;
    if (t == 0) rowptr[0] = 0;
}

__global__ void k_scan3(const int* __restrict__ boff, const int* __restrict__ counts,
                        int* __restrict__ rowptr, int* __restrict__ next,
                        float* __restrict__ dinv) {
    int i = blockIdx.x * 256 + threadIdx.x;
    if (i >= NND) return;
    int r = rowptr[i + 1] + boff[i >> 8];
    rowptr[i + 1] = r;
    next[i] = r - counts[i];
    dinv[i] = rsqrtf((float)counts[i] + 1.0f);  // +1 self loop
}

__global__ void k_scatter_p(const int* __restrict__ ei, int* next, int* csr) {
    int b = blockIdx.x;
    int g = b & (NXP - 1);
    int e = (b >> 3) * 256 + threadIdx.x;
    if (e >= NE) return;
    int d = ei[NE + e];
    if ((unsigned)(d - g * DPART) < (unsigned)DPART) {
        int pos = atomicAdd(&next[d], 1);
        csr[pos] = ei[e];
    }
}

// ---------------- GCNConv (fused gather + BN + ReLU + LN0 + PReLU0) ----------------

__global__ void k_conv1(const float* __restrict__ x, const float* __restrict__ W,
                        float* __restrict__ t0) {
    int tid = blockIdx.x * blockDim.x + threadIdx.x;
    if (tid >= NND * H) return;
    int n = tid >> 6, c = tid & 63;
    float acc = 0.f;
#pragma unroll
    for (int k = 0; k < FIN; k++) acc += x[n * FIN + k] * W[k * H + c];
    t0[n * H + c] = acc;
}

// wave per node; lane = 16*eg + q: eg = edge subgroup (0..3), q = channel quad
__global__ void k_gcn(const int* __restrict__ rowptr, const int* __restrict__ csr,
                      const float* __restrict__ t0, const float* __restrict__ dinv,
                      const float* __restrict__ cb, const float* __restrict__ bg,
                      const float* __restrict__ bb,
                      const float* __restrict__ lg, const float* __restrict__ lb,
                      const float* __restrict__ pa,
                      float* __restrict__ xc, float* __restrict__ u) {
    int d = (blockIdx.x * blockDim.x + threadIdx.x) >> 6;
    int lane = threadIdx.x & 63;
    if (d >= NND) return;
    int q = lane & 15, eg = lane >> 4;
    int beg = rowptr[d], end = rowptr[d + 1];
    float4 acc = {0.f, 0.f, 0.f, 0.f};
    for (int i0 = beg; i0 < end; i0 += 64) {
        int idx = i0 + lane;
        int csrv = 0; float dvv = 0.f;
        if (idx < end) { csrv = csr[idx]; dvv = dinv[csrv]; }
        int chunk = min(64, end - i0);
        for (int j = 0; j < chunk; j += 4) {
            int e_rel = j + eg;
            int s  = __shfl(csrv, e_rel, 64);
            float dv = __shfl(dvv, e_rel, 64);
            if (i0 + e_rel < end) {
                float4 tv = *(const float4*)&t0[s * H + 4 * q];
                acc.x += tv.x * dv; acc.y += tv.y * dv;
                acc.z += tv.z * dv; acc.w += tv.w * dv;
            }
        }
    }
#pragma unroll
    for (int off = 16; off <= 32; off <<= 1) {
        acc.x += __shfl_xor(acc.x, off, 64);
        acc.y += __shfl_xor(acc.y, off, 64);
        acc.z += __shfl_xor(acc.z, off, 64);
        acc.w += __shfl_xor(acc.w, off, 64);
    }
    if (eg == 0) {
        float dd = dinv[d];
        float4 ts = *(const float4*)&t0[d * H + 4 * q];
        float4 cbv = *(const float4*)&cb[4 * q];
        float4 bgv = *(const float4*)&bg[4 * q];
        float4 bbv = *(const float4*)&bb[4 * q];
        float bns = rsqrtf(1.f + EPS_BN);
        float4 x0;
        x0.x = fmaxf((acc.x * dd + ts.x * dd * dd + cbv.x) * (bgv.x * bns) + bbv.x, 0.f);
        x0.y = fmaxf((acc.y * dd + ts.y * dd * dd + cbv.y) * (bgv.y * bns) + bbv.y, 0.f);
        x0.z = fmaxf((acc.z * dd + ts.z * dd * dd + cbv.z) * (bgv.z * bns) + bbv.z, 0.f);
        x0.w = fmaxf((acc.w * dd + ts.w * dd * dd + cbv.w) * (bgv.w * bns) + bbv.w, 0.f);
        *(float4*)&xc[(size_t)d * H4 + 4 * q] = x0;
        // fused LN(layer0) + PReLU: reduce 64 channels over lanes 0..15
        float sum = (x0.x + x0.y) + (x0.z + x0.w);
        float sq  = (x0.x * x0.x + x0.y * x0.y) + (x0.z * x0.z + x0.w * x0.w);
#pragma unroll
        for (int off = 1; off <= 8; off <<= 1) {
            sum += __shfl_xor(sum, off, 64);
            sq  += __shfl_xor(sq,  off, 64);
        }
        float mu  = sum * (1.f / H);
        float var = sq * (1.f / H) - mu * mu;
        float rs = rsqrtf(var + EPS_BN);
        float4 lgv = *(const float4*)&lg[4 * q];
        float4 lbv = *(const float4*)&lb[4 * q];
        float4 pav = *(const float4*)&pa[4 * q];
        float4 y;
        y.x = (x0.x - mu) * rs * lgv.x + lbv.x;
        y.y = (x0.y - mu) * rs * lgv.y + lbv.y;
        y.z = (x0.z - mu) * rs * lgv.z + lbv.z;
        y.w = (x0.w - mu) * rs * lgv.w + lbv.w;
        y.x = (y.x >= 0.f) ? y.x : pav.x * y.x;
        y.y = (y.y >= 0.f) ? y.y : pav.y * y.y;
        y.z = (y.z >= 0.f) ? y.z : pav.z * y.z;
        y.w = (y.w >= 0.f) ? y.w : pav.w * y.w;
        *(float4*)&u[d * H + 4 * q] = y;
    }
}

// ---------------- GENConv softmax aggregation (vectorized gather) ----------------

__global__ void k_gen(const int* __restrict__ rowptr, const int* __restrict__ csr,
                      const float* __restrict__ u, const float* __restrict__ tptr,
                      int li, float* __restrict__ ua) {
    int d = (blockIdx.x * blockDim.x + threadIdx.x) >> 6;
    int lane = threadIdx.x & 63;
    if (d >= NND) return;
    int q = lane & 15, eg = lane >> 4;
    float t = tptr[li];
    int beg = rowptr[d], end = rowptr[d + 1];
    float4 s4 = {0.f, 0.f, 0.f, 0.f}, n4 = {0.f, 0.f, 0.f, 0.f};
    for (int i0 = beg; i0 < end; i0 += 64) {
        int idx = i0 + lane;
        int csrv = (idx < end) ? csr[idx] : 0;
        int chunk = min(64, end - i0);
        for (int j = 0; j < chunk; j += 4) {
            int e_rel = j + eg;
            int s = __shfl(csrv, e_rel, 64);
            if (i0 + e_rel < end) {
                float4 uv = *(const float4*)&u[s * H + 4 * q];
                float m0 = fmaxf(uv.x, 0.f) + EPS_MSG;
                float m1 = fmaxf(uv.y, 0.f) + EPS_MSG;
                float m2 = fmaxf(uv.z, 0.f) + EPS_MSG;
                float m3 = fmaxf(uv.w, 0.f) + EPS_MSG;
                float e0 = __expf(m0 * t - 8.f);
                float e1 = __expf(m1 * t - 8.f);
                float e2 = __expf(m2 * t - 8.f);
                float e3 = __expf(m3 * t - 8.f);
                s4.x += e0; s4.y += e1; s4.z += e2; s4.w += e3;
                n4.x += m0 * e0; n4.y += m1 * e1; n4.z += m2 * e2; n4.w += m3 * e3;
            }
        }
    }
#pragma unroll
    for (int off = 16; off <= 32; off <<= 1) {
        s4.x += __shfl_xor(s4.x, off, 64); s4.y += __shfl_xor(s4.y, off, 64);
        s4.z += __shfl_xor(s4.z, off, 64); s4.w += __shfl_xor(s4.w, off, 64);
        n4.x += __shfl_xor(n4.x, off, 64); n4.y += __shfl_xor(n4.y, off, 64);
        n4.z += __shfl_xor(n4.z, off, 64); n4.w += __shfl_xor(n4.w, off, 64);
    }
    if (eg == 0) {
        float4 us = *(const float4*)&u[d * H + 4 * q];
        float4 o;
        o.x = us.x + ((s4.x > 0.f) ? n4.x / s4.x : 0.f);
        o.y = us.y + ((s4.y > 0.f) ? n4.y / s4.y : 0.f);
        o.z = us.z + ((s4.z > 0.f) ? n4.z / s4.z : 0.f);
        o.w = us.w + ((s4.w > 0.f) ? n4.w / s4.w : 0.f);
        *(float4*)&ua[d * H + 4 * q] = o;
    }
}

// ---------------- fused MLP ----------------

__global__ void __launch_bounds__(256)
k_mlp(const float* __restrict__ ua,
      const float* __restrict__ W1, const float* __restrict__ b1,
      const float* __restrict__ bng, const float* __restrict__ bnb,
      const float* __restrict__ W2, const float* __restrict__ b2,
      float* __restrict__ xc, int slice,
      const float* __restrict__ lg, const float* __restrict__ lb,
      const float* __restrict__ pa, float* __restrict__ u_next, int do_ln) {
    __shared__ __align__(16) float u_t[64][36];
    __shared__ __align__(16) float z1_t[128][36];
    int t = threadIdx.x;
    int nb = blockIdx.x * 32;

#pragma unroll
    for (int r = 0; r < 8; r++) {
        int flat = t + 256 * r;
        int n = flat >> 6, c = flat & 63;
        int gn = nb + n;
        u_t[c][n] = (gn < NND) ? ua[gn * H + c] : 0.f;
    }
    __syncthreads();

    {
        int j = t & 127;
        int grp = t >> 7;
        int n0 = grp * 16;
        float acc[16];
#pragma unroll
        for (int m = 0; m < 16; m++) acc[m] = 0.f;
        for (int k = 0; k < 64; k++) {
            float w = W1[k * H2 + j];
            const float4* up = (const float4*)&u_t[k][n0];
            float4 a0 = up[0], a1 = up[1], a2 = up[2], a3 = up[3];
            acc[0]  += a0.x * w; acc[1]  += a0.y * w; acc[2]  += a0.z * w; acc[3]  += a0.w * w;
            acc[4]  += a1.x * w; acc[5]  += a1.y * w; acc[6]  += a1.z * w; acc[7]  += a1.w * w;
            acc[8]  += a2.x * w; acc[9]  += a2.y * w; acc[10] += a2.z * w; acc[11] += a2.w * w;
            acc[12] += a3.x * w; acc[13] += a3.y * w; acc[14] += a3.z * w; acc[15] += a3.w * w;
        }
        float b1v = b1[j];
        float bs = bng[j] * rsqrtf(1.f + EPS_BN);
        float bbv = bnb[j];
        float* zr = &z1_t[j][n0];
#pragma unroll
        for (int m = 0; m < 16; m++)
            zr[m] = fmaxf((acc[m] + b1v) * bs + bbv, 0.f);
    }
    __syncthreads();

    {
        int c = t & 63;
        int g2 = t >> 6;
        int m0 = g2 * 8;
        float acc[8];
#pragma unroll
        for (int m = 0; m < 8; m++) acc[m] = 0.f;
        for (int j = 0; j < 128; j++) {
            float w = W2[j * H + c];
            const float4* zp = (const float4*)&z1_t[j][m0];
            float4 z0 = zp[0], z1v = zp[1];
            acc[0] += z0.x * w;  acc[1] += z0.y * w;
            acc[2] += z0.z * w;  acc[3] += z0.w * w;
            acc[4] += z1v.x * w; acc[5] += z1v.y * w;
            acc[6] += z1v.z * w; acc[7] += z1v.w * w;
        }
        float b2v = b2[c];
        float lgv = 0.f, lbv = 0.f, pav = 0.f;
        if (do_ln) { lgv = lg[c]; lbv = lb[c]; pav = pa[c]; }
#pragma unroll
        for (int qq = 0; qq < 8; qq++) {
            int gn = nb + m0 + qq;
            float v = 0.f;
            if (gn < NND) {
                v = xc[(size_t)gn * H4 + slice * H + c] + acc[qq] + b2v;
                xc[(size_t)gn * H4 + (slice + 1) * H + c] = v;
            }
            if (do_ln) {
                float sum = v, sq = v * v;
#pragma unroll
                for (int off = 32; off >= 1; off >>= 1) {
                    sum += __shfl_xor(sum, off, 64);
                    sq  += __shfl_xor(sq,  off, 64);
                }
                float mu  = sum * (1.f / H);
                float var = sq * (1.f / H) - mu * mu;
                float y = (v - mu) * rsqrtf(var + EPS_BN) * lgv + lbv;
                if (gn < NND) u_next[gn * H + c] = (y >= 0.f) ? y : pav * y;
            }
        }
    }
}

// ---------------- pooling + readout ----------------

__global__ void k_pool(const float* __restrict__ xc, const int* __restrict__ batch,
                       float* __restrict__ p0) {
    int g = blockIdx.x;
    int c = threadIdx.x;
    int lo = 0, hi = NND;
    while (lo < hi) { int mid = (lo + hi) >> 1; if (batch[mid] < g) lo = mid + 1; else hi = mid; }
    int start = lo;
    hi = NND;
    while (lo < hi) { int mid = (lo + hi) >> 1; if (batch[mid] < g + 1) lo = mid + 1; else hi = mid; }
    int end = lo;
    float sum = 0.f, mx = -INFINITY;
    for (int n = start; n < end; n++) {
        float v = xc[(size_t)n * H4 + c];
        sum += v;
        mx = fmaxf(mx, v);
    }
    int cnt = end - start;
    p0[g * H8 + c] = sum / fmaxf((float)cnt, 1.f);
    p0[g * H8 + H4 + c] = (cnt > 0) ? mx : 0.f;
}

__global__ void k_lin1(const float* __restrict__ p0, const float* __restrict__ W,
                       const float* __restrict__ b, float* __restrict__ p1) {
    int tid = blockIdx.x * blockDim.x + threadIdx.x;
    int g = tid >> 7, j = tid & 127;
    if (g >= NG) return;
    float acc = 0.f;
    for (int k = 0; k < H8; k++) acc += p0[g * H8 + k] * W[k * H2 + j];
    p1[g * H2 + j] = fmaxf(acc + b[j], 0.f);
}

__global__ void k_lin2(const float* __restrict__ p1, const float* __restrict__ W,
                       const float* __restrict__ b, float* __restrict__ p2) {
    int tid = blockIdx.x * blockDim.x + threadIdx.x;
    int g = tid >> 6, c = tid & 63;
    if (g >= NG) return;
    float acc = 0.f;
#pragma unroll
    for (int k = 0; k < H2; k++) acc += p1[g * H2 + k] * W[k * H + c];
    p2[g * H + c] = fmaxf(acc + b[c], 0.f);
}

__global__ void k_out(const float* __restrict__ p2, const float* __restrict__ W,
                      const float* __restrict__ b, float* __restrict__ out) {
    int g = blockIdx.x * blockDim.x + threadIdx.x;
    if (g >= NG) return;
    float acc = 0.f;
#pragma unroll
    for (int k = 0; k < H; k++) acc += p2[g * H + k] * W[k];
    out[g] = acc + b[0];
}

extern "C" void kernel_launch(void* const* d_in, const int* in_sizes, int n_in,
                              void* d_out, int out_size, void* d_ws, size_t ws_size,
                              hipStream_t stream) {
    const float* x       = (const float*)d_in[0];
    const int*   ei      = (const int*)d_in[1];
    const int*   batch   = (const int*)d_in[2];
    const float* conv1_W = (const float*)d_in[3];
    const float* conv1_b = (const float*)d_in[4];
    const float* bn1_g   = (const float*)d_in[5];
    const float* bn1_b   = (const float*)d_in[6];
    const float* ln_g    = (const float*)d_in[7];
    const float* ln_b    = (const float*)d_in[8];
    const float* prelu_a = (const float*)d_in[9];
    const float* gen_t   = (const float*)d_in[10];
    const float* mlp_W1  = (const float*)d_in[11];
    const float* mlp_b1  = (const float*)d_in[12];
    const float* mlp_bng = (const float*)d_in[13];
    const float* mlp_bnb = (const float*)d_in[14];
    const float* mlp_W2  = (const float*)d_in[15];
    const float* mlp_b2  = (const float*)d_in[16];
    const float* lin1_W  = (const float*)d_in[17];
    const float* lin1_b  = (const float*)d_in[18];
    const float* lin2_W  = (const float*)d_in[19];
    const float* lin2_b  = (const float*)d_in[20];
    const float* out_W   = (const float*)d_in[21];
    const float* out_b   = (const float*)d_in[22];
    float* out = (float*)d_out;

    float* ws   = (float*)d_ws;
    float* xc   = ws;                          // NND*H4
    float* u    = xc + (size_t)NND * H4;       // NND*H
    float* ua   = u + (size_t)NND * H;         // NND*H (t0 aliases)
    float* t0   = ua;
    float* dinv = ua + (size_t)NND * H;        // NND
    int* rowptr = (int*)(dinv + NND);          // NND+1
    int* next   = rowptr + (NND + 1);          // NND
    int* counts = next + NND;                  // NND
    int* bsum   = counts + NND;                // NB
    int* boff   = bsum + NB;                   // NB
    int* csr    = boff + NB;                   // NE
    float* p0   = (float*)(csr + NE);          // NG*H8
    float* p1   = p0 + NG * H8;                // NG*H2
    float* p2   = p1 + NG * H2;                // NG*H

    const int B = 256;
    const int gN   = (NND + B - 1) / B;    // 196
    const int gNH  = (NND * H) / B;        // 12500
    const int gMLP = (NND + 31) / 32;      // 1563
    const int gEP  = NXP * ECH;            // 37504

    // ---- CSR build ----
    k_zero_counts<<<gN, B, 0, stream>>>(counts);
    k_count_p<<<gEP, B, 0, stream>>>(ei, counts);
    k_scan1<<<NB, B, 0, stream>>>(counts, rowptr, bsum);
    k_scan2<<<1, B, 0, stream>>>(bsum, boff, rowptr);
    k_scan3<<<NB, B, 0, stream>>>(boff, counts, rowptr, next, dinv);
    k_scatter_p<<<gEP, B, 0, stream>>>(ei, next, csr);

    // ---- GCNConv + LN0/PReLU0 ----
    k_conv1<<<gNH, B, 0, stream>>>(x, conv1_W, t0);
    k_gcn<<<gNH, B, 0, stream>>>(rowptr, csr, t0, dinv, conv1_b, bn1_g, bn1_b,
                                 ln_g, ln_b, prelu_a, xc, u);

    // ---- DeepGCN layers ----
    for (int i = 0; i < 3; i++) {
        k_gen<<<gNH, B, 0, stream>>>(rowptr, csr, u, gen_t, i, ua);
        int do_ln = (i < 2) ? 1 : 0;
        k_mlp<<<gMLP, B, 0, stream>>>(ua,
                                      mlp_W1 + (size_t)i * H * H2, mlp_b1 + i * H2,
                                      mlp_bng + i * H2, mlp_bnb + i * H2,
                                      mlp_W2 + (size_t)i * H2 * H, mlp_b2 + i * H,
                                      xc, i,
                                      ln_g + (i + 1) * H, ln_b + (i + 1) * H,
                                      prelu_a + (i + 1) * H, u, do_ln);
    }

    // ---- pooling + readout ----
    k_pool<<<NG, H4, 0, stream>>>(xc, batch, p0);
    k_lin1<<<(NG * H2) / B, B, 0, stream>>>(p0, lin1_W, lin1_b, p1);
    k_lin2<<<(NG * H) / B, B, 0, stream>>>(p1, lin2_W, lin2_b, p2);
    k_out<<<1, NG, 0, stream>>>(p2, out_W, out_b, out);
}

// Round 5
// 563.633 us; speedup vs baseline: 6.2446x; 1.1128x over previous
//
#include <hip/hip_runtime.h>
#include <math.h>

#define NND 50000
#define NE  1200000
#define NG  256
#define H   64
#define H2  128
#define H4  256
#define H8  512
#define FIN 5
#define EPS_BN 1e-5f
#define EPS_MSG 1e-7f
#define NB 196          // ceil(NND/256)
#define NXP 8           // XCD partitions
#define DPART 6250      // NND / NXP
#define ECH 4688        // ceil(NE/256)
#define PC 8            // pool chunks per graph

// ---------------- CSR build (by dst), XCD-partitioned ----------------

__global__ void k_zero_counts(int* counts) {
    int n = blockIdx.x * blockDim.x + threadIdx.x;
    if (n < NND) counts[n] = 0;
}

__global__ void k_count_p(const int* __restrict__ ei, int* counts) {
    int b = blockIdx.x;
    int g = b & (NXP - 1);
    int e = (b >> 3) * 256 + threadIdx.x;
    if (e >= NE) return;
    int d = ei[NE + e];
    if ((unsigned)(d - g * DPART) < (unsigned)DPART) atomicAdd(&counts[d], 1);
}

__global__ void k_scan1(const int* __restrict__ counts, int* __restrict__ rowptr,
                        int* __restrict__ bsum) {
    __shared__ int wsum[4];
    int b = blockIdx.x, t = threadIdx.x;
    int i = b * 256 + t;
    int v = (i < NND) ? counts[i] : 0;
    int lane = t & 63, wid = t >> 6;
    int sv = v;
#pragma unroll
    for (int off = 1; off < 64; off <<= 1) {
        int x = __shfl_up(sv, off, 64);
        if (lane >= off) sv += x;
    }
    if (lane == 63) wsum[wid] = sv;
    __syncthreads();
    int woff = 0;
    for (int w = 0; w < wid; w++) woff += wsum[w];
    int inc = woff + sv;
    if (i < NND) rowptr[i + 1] = inc;
    if (t == 255) bsum[b] = inc;
}

__global__ void k_scan2(const int* __restrict__ bsum, int* __restrict__ boff,
                        int* __restrict__ rowptr) {
    __shared__ int wsum[4];
    int t = threadIdx.x;
    int v = (t < NB) ? bsum[t] : 0;
    int lane = t & 63, wid = t >> 6;
    int sv = v;
#pragma unroll
    for (int off = 1; off < 64; off <<= 1) {
        int x = __shfl_up(sv, off, 64);
        if (lane >= off) sv += x;
    }
    if (lane == 63) wsum[wid] = sv;
    __syncthreads();
    int woff = 0;
    for (int w = 0; w < wid; w++) woff += wsum[w];
    if (t < NB) boff[t] = woff + sv - v;
    if (t == 0) rowptr[0] = 0;
}

__global__ void k_scan3(const int* __restrict__ boff, const int* __restrict__ counts,
                        int* __restrict__ rowptr, int* __restrict__ next,
                        float* __restrict__ dinv) {
    int i = blockIdx.x * 256 + threadIdx.x;
    if (i >= NND) return;
    int r = rowptr[i + 1] + boff[i >> 8];
    rowptr[i + 1] = r;
    next[i] = r - counts[i];
    dinv[i] = rsqrtf((float)counts[i] + 1.0f);
}

__global__ void k_scatter_p(const int* __restrict__ ei, int* next, int* csr) {
    int b = blockIdx.x;
    int g = b & (NXP - 1);
    int e = (b >> 3) * 256 + threadIdx.x;
    if (e >= NE) return;
    int d = ei[NE + e];
    if ((unsigned)(d - g * DPART) < (unsigned)DPART) {
        int pos = atomicAdd(&next[d], 1);
        csr[pos] = ei[e];
    }
}

// ---------------- GCNConv (fused gather + BN + ReLU + LN0 + PReLU0) ----------------

__global__ void k_conv1(const float* __restrict__ x, const float* __restrict__ W,
                        float* __restrict__ t0) {
    int tid = blockIdx.x * blockDim.x + threadIdx.x;
    if (tid >= NND * H) return;
    int n = tid >> 6, c = tid & 63;
    float acc = 0.f;
#pragma unroll
    for (int k = 0; k < FIN; k++) acc += x[n * FIN + k] * W[k * H + c];
    t0[n * H + c] = acc;
}

__global__ void k_gcn(const int* __restrict__ rowptr, const int* __restrict__ csr,
                      const float* __restrict__ t0, const float* __restrict__ dinv,
                      const float* __restrict__ cb, const float* __restrict__ bg,
                      const float* __restrict__ bb,
                      const float* __restrict__ lg, const float* __restrict__ lb,
                      const float* __restrict__ pa,
                      float* __restrict__ xc, float* __restrict__ u) {
    int d = (blockIdx.x * blockDim.x + threadIdx.x) >> 6;
    int lane = threadIdx.x & 63;
    if (d >= NND) return;
    int q = lane & 15, eg = lane >> 4;
    int beg = rowptr[d], end = rowptr[d + 1];
    float4 acc = {0.f, 0.f, 0.f, 0.f};
    for (int i0 = beg; i0 < end; i0 += 64) {
        int idx = i0 + lane;
        int csrv = 0; float dvv = 0.f;
        if (idx < end) { csrv = csr[idx]; dvv = dinv[csrv]; }
        int chunk = min(64, end - i0);
        for (int j = 0; j < chunk; j += 4) {
            int e_rel = j + eg;
            int s  = __shfl(csrv, e_rel, 64);
            float dv = __shfl(dvv, e_rel, 64);
            if (i0 + e_rel < end) {
                float4 tv = *(const float4*)&t0[s * H + 4 * q];
                acc.x += tv.x * dv; acc.y += tv.y * dv;
                acc.z += tv.z * dv; acc.w += tv.w * dv;
            }
        }
    }
#pragma unroll
    for (int off = 16; off <= 32; off <<= 1) {
        acc.x += __shfl_xor(acc.x, off, 64);
        acc.y += __shfl_xor(acc.y, off, 64);
        acc.z += __shfl_xor(acc.z, off, 64);
        acc.w += __shfl_xor(acc.w, off, 64);
    }
    if (eg == 0) {
        float dd = dinv[d];
        float4 ts = *(const float4*)&t0[d * H + 4 * q];
        float4 cbv = *(const float4*)&cb[4 * q];
        float4 bgv = *(const float4*)&bg[4 * q];
        float4 bbv = *(const float4*)&bb[4 * q];
        float bns = rsqrtf(1.f + EPS_BN);
        float4 x0;
        x0.x = fmaxf((acc.x * dd + ts.x * dd * dd + cbv.x) * (bgv.x * bns) + bbv.x, 0.f);
        x0.y = fmaxf((acc.y * dd + ts.y * dd * dd + cbv.y) * (bgv.y * bns) + bbv.y, 0.f);
        x0.z = fmaxf((acc.z * dd + ts.z * dd * dd + cbv.z) * (bgv.z * bns) + bbv.z, 0.f);
        x0.w = fmaxf((acc.w * dd + ts.w * dd * dd + cbv.w) * (bgv.w * bns) + bbv.w, 0.f);
        *(float4*)&xc[(size_t)d * H4 + 4 * q] = x0;
        float sum = (x0.x + x0.y) + (x0.z + x0.w);
        float sq  = (x0.x * x0.x + x0.y * x0.y) + (x0.z * x0.z + x0.w * x0.w);
#pragma unroll
        for (int off = 1; off <= 8; off <<= 1) {
            sum += __shfl_xor(sum, off, 64);
            sq  += __shfl_xor(sq,  off, 64);
        }
        float mu  = sum * (1.f / H);
        float var = sq * (1.f / H) - mu * mu;
        float rs = rsqrtf(var + EPS_BN);
        float4 lgv = *(const float4*)&lg[4 * q];
        float4 lbv = *(const float4*)&lb[4 * q];
        float4 pav = *(const float4*)&pa[4 * q];
        float4 y;
        y.x = (x0.x - mu) * rs * lgv.x + lbv.x;
        y.y = (x0.y - mu) * rs * lgv.y + lbv.y;
        y.z = (x0.z - mu) * rs * lgv.z + lbv.z;
        y.w = (x0.w - mu) * rs * lgv.w + lbv.w;
        y.x = (y.x >= 0.f) ? y.x : pav.x * y.x;
        y.y = (y.y >= 0.f) ? y.y : pav.y * y.y;
        y.z = (y.z >= 0.f) ? y.z : pav.z * y.z;
        y.w = (y.w >= 0.f) ? y.w : pav.w * y.w;
        *(float4*)&u[d * H + 4 * q] = y;
    }
}

// ---------------- GENConv softmax aggregation (vectorized gather) ----------------

__global__ void k_gen(const int* __restrict__ rowptr, const int* __restrict__ csr,
                      const float* __restrict__ u, const float* __restrict__ tptr,
                      int li, float* __restrict__ ua) {
    int d = (blockIdx.x * blockDim.x + threadIdx.x) >> 6;
    int lane = threadIdx.x & 63;
    if (d >= NND) return;
    int q = lane & 15, eg = lane >> 4;
    float t = tptr[li];
    int beg = rowptr[d], end = rowptr[d + 1];
    float4 s4 = {0.f, 0.f, 0.f, 0.f}, n4 = {0.f, 0.f, 0.f, 0.f};
    for (int i0 = beg; i0 < end; i0 += 64) {
        int idx = i0 + lane;
        int csrv = (idx < end) ? csr[idx] : 0;
        int chunk = min(64, end - i0);
        for (int j = 0; j < chunk; j += 4) {
            int e_rel = j + eg;
            int s = __shfl(csrv, e_rel, 64);
            if (i0 + e_rel < end) {
                float4 uv = *(const float4*)&u[s * H + 4 * q];
                float m0 = fmaxf(uv.x, 0.f) + EPS_MSG;
                float m1 = fmaxf(uv.y, 0.f) + EPS_MSG;
                float m2 = fmaxf(uv.z, 0.f) + EPS_MSG;
                float m3 = fmaxf(uv.w, 0.f) + EPS_MSG;
                float e0 = __expf(m0 * t - 8.f);
                float e1 = __expf(m1 * t - 8.f);
                float e2 = __expf(m2 * t - 8.f);
                float e3 = __expf(m3 * t - 8.f);
                s4.x += e0; s4.y += e1; s4.z += e2; s4.w += e3;
                n4.x += m0 * e0; n4.y += m1 * e1; n4.z += m2 * e2; n4.w += m3 * e3;
            }
        }
    }
#pragma unroll
    for (int off = 16; off <= 32; off <<= 1) {
        s4.x += __shfl_xor(s4.x, off, 64); s4.y += __shfl_xor(s4.y, off, 64);
        s4.z += __shfl_xor(s4.z, off, 64); s4.w += __shfl_xor(s4.w, off, 64);
        n4.x += __shfl_xor(n4.x, off, 64); n4.y += __shfl_xor(n4.y, off, 64);
        n4.z += __shfl_xor(n4.z, off, 64); n4.w += __shfl_xor(n4.w, off, 64);
    }
    if (eg == 0) {
        float4 us = *(const float4*)&u[d * H + 4 * q];
        float4 o;
        o.x = us.x + ((s4.x > 0.f) ? n4.x / s4.x : 0.f);
        o.y = us.y + ((s4.y > 0.f) ? n4.y / s4.y : 0.f);
        o.z = us.z + ((s4.z > 0.f) ? n4.z / s4.z : 0.f);
        o.w = us.w + ((s4.w > 0.f) ? n4.w / s4.w : 0.f);
        *(float4*)&ua[d * H + 4 * q] = o;
    }
}

// ---------------- fused MLP ----------------

__global__ void __launch_bounds__(256)
k_mlp(const float* __restrict__ ua,
      const float* __restrict__ W1, const float* __restrict__ b1,
      const float* __restrict__ bng, const float* __restrict__ bnb,
      const float* __restrict__ W2, const float* __restrict__ b2,
      float* __restrict__ xc, int slice,
      const float* __restrict__ lg, const float* __restrict__ lb,
      const float* __restrict__ pa, float* __restrict__ u_next, int do_ln) {
    __shared__ __align__(16) float u_t[64][36];
    __shared__ __align__(16) float z1_t[128][36];
    int t = threadIdx.x;
    int nb = blockIdx.x * 32;

#pragma unroll
    for (int r = 0; r < 8; r++) {
        int flat = t + 256 * r;
        int n = flat >> 6, c = flat & 63;
        int gn = nb + n;
        u_t[c][n] = (gn < NND) ? ua[gn * H + c] : 0.f;
    }
    __syncthreads();

    {
        int j = t & 127;
        int grp = t >> 7;
        int n0 = grp * 16;
        float acc[16];
#pragma unroll
        for (int m = 0; m < 16; m++) acc[m] = 0.f;
        for (int k = 0; k < 64; k++) {
            float w = W1[k * H2 + j];
            const float4* up = (const float4*)&u_t[k][n0];
            float4 a0 = up[0], a1 = up[1], a2 = up[2], a3 = up[3];
            acc[0]  += a0.x * w; acc[1]  += a0.y * w; acc[2]  += a0.z * w; acc[3]  += a0.w * w;
            acc[4]  += a1.x * w; acc[5]  += a1.y * w; acc[6]  += a1.z * w; acc[7]  += a1.w * w;
            acc[8]  += a2.x * w; acc[9]  += a2.y * w; acc[10] += a2.z * w; acc[11] += a2.w * w;
            acc[12] += a3.x * w; acc[13] += a3.y * w; acc[14] += a3.z * w; acc[15] += a3.w * w;
        }
        float b1v = b1[j];
        float bs = bng[j] * rsqrtf(1.f + EPS_BN);
        float bbv = bnb[j];
        float* zr = &z1_t[j][n0];
#pragma unroll
        for (int m = 0; m < 16; m++)
            zr[m] = fmaxf((acc[m] + b1v) * bs + bbv, 0.f);
    }
    __syncthreads();

    {
        int c = t & 63;
        int g2 = t >> 6;
        int m0 = g2 * 8;
        float acc[8];
#pragma unroll
        for (int m = 0; m < 8; m++) acc[m] = 0.f;
        for (int j = 0; j < 128; j++) {
            float w = W2[j * H + c];
            const float4* zp = (const float4*)&z1_t[j][m0];
            float4 z0 = zp[0], z1v = zp[1];
            acc[0] += z0.x * w;  acc[1] += z0.y * w;
            acc[2] += z0.z * w;  acc[3] += z0.w * w;
            acc[4] += z1v.x * w; acc[5] += z1v.y * w;
            acc[6] += z1v.z * w; acc[7] += z1v.w * w;
        }
        float b2v = b2[c];
        float lgv = 0.f, lbv = 0.f, pav = 0.f;
        if (do_ln) { lgv = lg[c]; lbv = lb[c]; pav = pa[c]; }
#pragma unroll
        for (int qq = 0; qq < 8; qq++) {
            int gn = nb + m0 + qq;
            float v = 0.f;
            if (gn < NND) {
                v = xc[(size_t)gn * H4 + slice * H + c] + acc[qq] + b2v;
                xc[(size_t)gn * H4 + (slice + 1) * H + c] = v;
            }
            if (do_ln) {
                float sum = v, sq = v * v;
#pragma unroll
                for (int off = 32; off >= 1; off >>= 1) {
                    sum += __shfl_xor(sum, off, 64);
                    sq  += __shfl_xor(sq,  off, 64);
                }
                float mu  = sum * (1.f / H);
                float var = sq * (1.f / H) - mu * mu;
                float y = (v - mu) * rsqrtf(var + EPS_BN) * lgv + lbv;
                if (gn < NND) u_next[gn * H + c] = (y >= 0.f) ? y : pav * y;
            }
        }
    }
}

// ---------------- pooling + readout ----------------

// gstart[g] = first node of graph g (batch sorted); gstart[NG] = NND
__global__ void k_gbounds(const int* __restrict__ batch, int* __restrict__ gstart) {
    int g = threadIdx.x + blockIdx.x * blockDim.x;
    if (g > NG) return;
    int lo = 0, hi = NND;
    while (lo < hi) { int mid = (lo + hi) >> 1; if (batch[mid] < g) lo = mid + 1; else hi = mid; }
    gstart[g] = lo;
}

// grid = NG*PC; block reduces chunk k of graph g into partials (no atomics)
__global__ void __launch_bounds__(256)
k_pool1(const float* __restrict__ xc, const int* __restrict__ gstart,
        float* __restrict__ psum_p, float* __restrict__ pmax_p) {
    __shared__ float4 ssum[256];
    __shared__ float4 smax[256];
    int b = blockIdx.x;
    int g = b >> 3, k = b & (PC - 1);
    int t = threadIdx.x;
    int start = gstart[g], end = gstart[g + 1];
    int len = end - start;
    int c0 = start + (len * k) / PC;
    int c1 = start + (len * (k + 1)) / PC;
    int q = t & 63, sub = t >> 6;
    float4 sum = {0.f, 0.f, 0.f, 0.f};
    float4 mx = {-INFINITY, -INFINITY, -INFINITY, -INFINITY};
    for (int n = c0 + sub; n < c1; n += 4) {
        float4 v = *(const float4*)&xc[(size_t)n * H4 + 4 * q];
        sum.x += v.x; sum.y += v.y; sum.z += v.z; sum.w += v.w;
        mx.x = fmaxf(mx.x, v.x); mx.y = fmaxf(mx.y, v.y);
        mx.z = fmaxf(mx.z, v.z); mx.w = fmaxf(mx.w, v.w);
    }
    ssum[t] = sum; smax[t] = mx;
    __syncthreads();
    if (t < 64) {
        float4 s0 = ssum[t], s1 = ssum[t + 64], s2 = ssum[t + 128], s3 = ssum[t + 192];
        float4 m0 = smax[t], m1 = smax[t + 64], m2 = smax[t + 128], m3 = smax[t + 192];
        float4 S, M;
        S.x = (s0.x + s1.x) + (s2.x + s3.x);
        S.y = (s0.y + s1.y) + (s2.y + s3.y);
        S.z = (s0.z + s1.z) + (s2.z + s3.z);
        S.w = (s0.w + s1.w) + (s2.w + s3.w);
        M.x = fmaxf(fmaxf(m0.x, m1.x), fmaxf(m2.x, m3.x));
        M.y = fmaxf(fmaxf(m0.y, m1.y), fmaxf(m2.y, m3.y));
        M.z = fmaxf(fmaxf(m0.z, m1.z), fmaxf(m2.z, m3.z));
        M.w = fmaxf(fmaxf(m0.w, m1.w), fmaxf(m2.w, m3.w));
        *(float4*)&psum_p[(size_t)b * H4 + 4 * q] = S;
        *(float4*)&pmax_p[(size_t)b * H4 + 4 * q] = M;
    }
}

// one block per graph: reduce PC partials -> p0 (LDS) -> lin1 -> lin2 -> out
__global__ void __launch_bounds__(256)
k_readout(const float* __restrict__ psum_p, const float* __restrict__ pmax_p,
          const int* __restrict__ gstart,
          const float* __restrict__ W1, const float* __restrict__ b1,
          const float* __restrict__ W2, const float* __restrict__ b2,
          const float* __restrict__ Wo, const float* __restrict__ bo,
          float* __restrict__ out) {
    __shared__ float p0_l[H8];
    __shared__ float p1part[2][H2];
    __shared__ float p1_l[H2];
    __shared__ float p2part[4][H];
    __shared__ float p2_l[H];
    int g = blockIdx.x;
    int t = threadIdx.x;

    // reduce partials: thread t = channel c
    {
        float s = 0.f, m = -INFINITY;
#pragma unroll
        for (int k = 0; k < PC; k++) {
            s += psum_p[(size_t)(g * PC + k) * H4 + t];
            m = fmaxf(m, pmax_p[(size_t)(g * PC + k) * H4 + t]);
        }
        int cnt = gstart[g + 1] - gstart[g];
        p0_l[t] = s / fmaxf((float)cnt, 1.f);
        p0_l[H4 + t] = (cnt > 0) ? m : 0.f;
    }
    __syncthreads();

    // lin1: 512 -> 128, split k-range over 2 halves
    {
        int j = t & 127, h = t >> 7;
        float acc = 0.f;
        int k0 = h * 256;
        for (int k = 0; k < 256; k++) acc += p0_l[k0 + k] * W1[(k0 + k) * H2 + j];
        p1part[h][j] = acc;
    }
    __syncthreads();
    if (t < H2) p1_l[t] = fmaxf(p1part[0][t] + p1part[1][t] + b1[t], 0.f);
    __syncthreads();

    // lin2: 128 -> 64, split k-range over 4 quarters
    {
        int c = t & 63, h = t >> 6;
        float acc = 0.f;
        int k0 = h * 32;
        for (int k = 0; k < 32; k++) acc += p1_l[k0 + k] * W2[(k0 + k) * H + c];
        p2part[h][c] = acc;
    }
    __syncthreads();
    if (t < H) p2_l[t] = fmaxf(((p2part[0][t] + p2part[1][t]) + (p2part[2][t] + p2part[3][t])) + b2[t], 0.f);
    __syncthreads();

    // out: 64 -> 1 wave reduce
    if (t < 64) {
        float v = p2_l[t] * Wo[t];
#pragma unroll
        for (int off = 32; off >= 1; off >>= 1) v += __shfl_xor(v, off, 64);
        if (t == 0) out[g] = v + bo[0];
    }
}

extern "C" void kernel_launch(void* const* d_in, const int* in_sizes, int n_in,
                              void* d_out, int out_size, void* d_ws, size_t ws_size,
                              hipStream_t stream) {
    const float* x       = (const float*)d_in[0];
    const int*   ei      = (const int*)d_in[1];
    const int*   batch   = (const int*)d_in[2];
    const float* conv1_W = (const float*)d_in[3];
    const float* conv1_b = (const float*)d_in[4];
    const float* bn1_g   = (const float*)d_in[5];
    const float* bn1_b   = (const float*)d_in[6];
    const float* ln_g    = (const float*)d_in[7];
    const float* ln_b    = (const float*)d_in[8];
    const float* prelu_a = (const float*)d_in[9];
    const float* gen_t   = (const float*)d_in[10];
    const float* mlp_W1  = (const float*)d_in[11];
    const float* mlp_b1  = (const float*)d_in[12];
    const float* mlp_bng = (const float*)d_in[13];
    const float* mlp_bnb = (const float*)d_in[14];
    const float* mlp_W2  = (const float*)d_in[15];
    const float* mlp_b2  = (const float*)d_in[16];
    const float* lin1_W  = (const float*)d_in[17];
    const float* lin1_b  = (const float*)d_in[18];
    const float* lin2_W  = (const float*)d_in[19];
    const float* lin2_b  = (const float*)d_in[20];
    const float* out_W   = (const float*)d_in[21];
    const float* out_b   = (const float*)d_in[22];
    float* out = (float*)d_out;

    float* ws   = (float*)d_ws;
    float* xc   = ws;                          // NND*H4
    float* u    = xc + (size_t)NND * H4;       // NND*H
    float* ua   = u + (size_t)NND * H;         // NND*H (t0 aliases)
    float* t0   = ua;
    float* dinv = ua + (size_t)NND * H;        // NND
    int* rowptr = (int*)(dinv + NND);          // NND+1
    int* next   = rowptr + (NND + 1);          // NND
    int* counts = next + NND;                  // NND
    int* bsum   = counts + NND;                // NB
    int* boff   = bsum + NB;                   // NB
    int* csr    = boff + NB;                   // NE
    float* psum_p = (float*)(csr + NE);        // NG*PC*H4
    float* pmax_p = psum_p + (size_t)NG * PC * H4;  // NG*PC*H4
    int* gstart = (int*)(pmax_p + (size_t)NG * PC * H4);  // NG+1

    const int B = 256;
    const int gN   = (NND + B - 1) / B;    // 196
    const int gNH  = (NND * H) / B;        // 12500
    const int gMLP = (NND + 31) / 32;      // 1563
    const int gEP  = NXP * ECH;            // 37504

    // ---- CSR build ----
    k_zero_counts<<<gN, B, 0, stream>>>(counts);
    k_count_p<<<gEP, B, 0, stream>>>(ei, counts);
    k_scan1<<<NB, B, 0, stream>>>(counts, rowptr, bsum);
    k_scan2<<<1, B, 0, stream>>>(bsum, boff, rowptr);
    k_scan3<<<NB, B, 0, stream>>>(boff, counts, rowptr, next, dinv);
    k_scatter_p<<<gEP, B, 0, stream>>>(ei, next, csr);
    k_gbounds<<<2, 256, 0, stream>>>(batch, gstart);

    // ---- GCNConv + LN0/PReLU0 ----
    k_conv1<<<gNH, B, 0, stream>>>(x, conv1_W, t0);
    k_gcn<<<gNH, B, 0, stream>>>(rowptr, csr, t0, dinv, conv1_b, bn1_g, bn1_b,
                                 ln_g, ln_b, prelu_a, xc, u);

    // ---- DeepGCN layers ----
    for (int i = 0; i < 3; i++) {
        k_gen<<<gNH, B, 0, stream>>>(rowptr, csr, u, gen_t, i, ua);
        int do_ln = (i < 2) ? 1 : 0;
        k_mlp<<<gMLP, B, 0, stream>>>(ua,
                                      mlp_W1 + (size_t)i * H * H2, mlp_b1 + i * H2,
                                      mlp_bng + i * H2, mlp_bnb + i * H2,
                                      mlp_W2 + (size_t)i * H2 * H, mlp_b2 + i * H,
                                      xc, i,
                                      ln_g + (i + 1) * H, ln_b + (i + 1) * H,
                                      prelu_a + (i + 1) * H, u, do_ln);
    }

    // ---- pooling + readout ----
    k_pool1<<<NG * PC, B, 0, stream>>>(xc, gstart, psum_p, pmax_p);
    k_readout<<<NG, B, 0, stream>>>(psum_p, pmax_p, gstart,
                                    lin1_W, lin1_b, lin2_W, lin2_b, out_W, out_b, out);
}

// Round 6
// 559.751 us; speedup vs baseline: 6.2879x; 1.0069x over previous
//
#include <hip/hip_runtime.h>
#include <math.h>

#define NND 50000
#define NE  1200000
#define NG  256
#define H   64
#define H2  128
#define H4  256
#define H8  512
#define FIN 5
#define EPS_BN 1e-5f
#define EPS_MSG 1e-7f
#define NB 196          // ceil(NND/256)
#define NXP 8           // XCD partitions
#define DPART 6250      // NND / NXP
#define ECH 4688        // ceil(NE/256)
#define PC 8            // pool chunks per graph
#define MT 64           // nodes per mlp block

// ---------------- CSR build (by dst), XCD-partitioned ----------------

__global__ void k_zero_counts(int* counts) {
    int n = blockIdx.x * blockDim.x + threadIdx.x;
    if (n < NND) counts[n] = 0;
}

__global__ void k_count_p(const int* __restrict__ ei, int* counts) {
    int b = blockIdx.x;
    int g = b & (NXP - 1);
    int e = (b >> 3) * 256 + threadIdx.x;
    if (e >= NE) return;
    int d = ei[NE + e];
    if ((unsigned)(d - g * DPART) < (unsigned)DPART) atomicAdd(&counts[d], 1);
}

__global__ void k_scan1(const int* __restrict__ counts, int* __restrict__ rowptr,
                        int* __restrict__ bsum) {
    __shared__ int wsum[4];
    int b = blockIdx.x, t = threadIdx.x;
    int i = b * 256 + t;
    int v = (i < NND) ? counts[i] : 0;
    int lane = t & 63, wid = t >> 6;
    int sv = v;
#pragma unroll
    for (int off = 1; off < 64; off <<= 1) {
        int x = __shfl_up(sv, off, 64);
        if (lane >= off) sv += x;
    }
    if (lane == 63) wsum[wid] = sv;
    __syncthreads();
    int woff = 0;
    for (int w = 0; w < wid; w++) woff += wsum[w];
    int inc = woff + sv;
    if (i < NND) rowptr[i + 1] = inc;
    if (t == 255) bsum[b] = inc;
}

__global__ void k_scan2(const int* __restrict__ bsum, int* __restrict__ boff,
                        int* __restrict__ rowptr) {
    __shared__ int wsum[4];
    int t = threadIdx.x;
    int v = (t < NB) ? bsum[t] : 0;
    int lane = t & 63, wid = t >> 6;
    int sv = v;
#pragma unroll
    for (int off = 1; off < 64; off <<= 1) {
        int x = __shfl_up(sv, off, 64);
        if (lane >= off) sv += x;
    }
    if (lane == 63) wsum[wid] = sv;
    __syncthreads();
    int woff = 0;
    for (int w = 0; w < wid; w++) woff += wsum[w];
    if (t < NB) boff[t] = woff + sv - v;
    if (t == 0) rowptr[0] = 0;
}

__global__ void k_scan3(const int* __restrict__ boff, const int* __restrict__ counts,
                        int* __restrict__ rowptr, int* __restrict__ next,
                        float* __restrict__ dinv) {
    int i = blockIdx.x * 256 + threadIdx.x;
    if (i >= NND) return;
    int r = rowptr[i + 1] + boff[i >> 8];
    rowptr[i + 1] = r;
    next[i] = r - counts[i];
    dinv[i] = rsqrtf((float)counts[i] + 1.0f);
}

__global__ void k_scatter_p(const int* __restrict__ ei, int* next, int* csr) {
    int b = blockIdx.x;
    int g = b & (NXP - 1);
    int e = (b >> 3) * 256 + threadIdx.x;
    if (e >= NE) return;
    int d = ei[NE + e];
    if ((unsigned)(d - g * DPART) < (unsigned)DPART) {
        int pos = atomicAdd(&next[d], 1);
        csr[pos] = ei[e];
    }
}

// ---------------- GCNConv (fused gather + BN + ReLU + LN0 + PReLU0) ----------------

__global__ void k_conv1(const float* __restrict__ x, const float* __restrict__ W,
                        float* __restrict__ t0) {
    int tid = blockIdx.x * blockDim.x + threadIdx.x;
    if (tid >= NND * H) return;
    int n = tid >> 6, c = tid & 63;
    float acc = 0.f;
#pragma unroll
    for (int k = 0; k < FIN; k++) acc += x[n * FIN + k] * W[k * H + c];
    t0[n * H + c] = acc;
}

__global__ void k_gcn(const int* __restrict__ rowptr, const int* __restrict__ csr,
                      const float* __restrict__ t0, const float* __restrict__ dinv,
                      const float* __restrict__ cb, const float* __restrict__ bg,
                      const float* __restrict__ bb,
                      const float* __restrict__ lg, const float* __restrict__ lb,
                      const float* __restrict__ pa,
                      float* __restrict__ xc, float* __restrict__ u) {
    int d = (blockIdx.x * blockDim.x + threadIdx.x) >> 6;
    int lane = threadIdx.x & 63;
    if (d >= NND) return;
    int q = lane & 15, eg = lane >> 4;
    int beg = rowptr[d], end = rowptr[d + 1];
    float4 acc = {0.f, 0.f, 0.f, 0.f};
    for (int i0 = beg; i0 < end; i0 += 64) {
        int idx = i0 + lane;
        int csrv = 0; float dvv = 0.f;
        if (idx < end) { csrv = csr[idx]; dvv = dinv[csrv]; }
        int chunk = min(64, end - i0);
        for (int j = 0; j < chunk; j += 4) {
            int e_rel = j + eg;
            int s  = __shfl(csrv, e_rel, 64);
            float dv = __shfl(dvv, e_rel, 64);
            if (i0 + e_rel < end) {
                float4 tv = *(const float4*)&t0[s * H + 4 * q];
                acc.x += tv.x * dv; acc.y += tv.y * dv;
                acc.z += tv.z * dv; acc.w += tv.w * dv;
            }
        }
    }
#pragma unroll
    for (int off = 16; off <= 32; off <<= 1) {
        acc.x += __shfl_xor(acc.x, off, 64);
        acc.y += __shfl_xor(acc.y, off, 64);
        acc.z += __shfl_xor(acc.z, off, 64);
        acc.w += __shfl_xor(acc.w, off, 64);
    }
    if (eg == 0) {
        float dd = dinv[d];
        float4 ts = *(const float4*)&t0[d * H + 4 * q];
        float4 cbv = *(const float4*)&cb[4 * q];
        float4 bgv = *(const float4*)&bg[4 * q];
        float4 bbv = *(const float4*)&bb[4 * q];
        float bns = rsqrtf(1.f + EPS_BN);
        float4 x0;
        x0.x = fmaxf((acc.x * dd + ts.x * dd * dd + cbv.x) * (bgv.x * bns) + bbv.x, 0.f);
        x0.y = fmaxf((acc.y * dd + ts.y * dd * dd + cbv.y) * (bgv.y * bns) + bbv.y, 0.f);
        x0.z = fmaxf((acc.z * dd + ts.z * dd * dd + cbv.z) * (bgv.z * bns) + bbv.z, 0.f);
        x0.w = fmaxf((acc.w * dd + ts.w * dd * dd + cbv.w) * (bgv.w * bns) + bbv.w, 0.f);
        *(float4*)&xc[(size_t)d * H4 + 4 * q] = x0;
        float sum = (x0.x + x0.y) + (x0.z + x0.w);
        float sq  = (x0.x * x0.x + x0.y * x0.y) + (x0.z * x0.z + x0.w * x0.w);
#pragma unroll
        for (int off = 1; off <= 8; off <<= 1) {
            sum += __shfl_xor(sum, off, 64);
            sq  += __shfl_xor(sq,  off, 64);
        }
        float mu  = sum * (1.f / H);
        float var = sq * (1.f / H) - mu * mu;
        float rs = rsqrtf(var + EPS_BN);
        float4 lgv = *(const float4*)&lg[4 * q];
        float4 lbv = *(const float4*)&lb[4 * q];
        float4 pav = *(const float4*)&pa[4 * q];
        float4 y;
        y.x = (x0.x - mu) * rs * lgv.x + lbv.x;
        y.y = (x0.y - mu) * rs * lgv.y + lbv.y;
        y.z = (x0.z - mu) * rs * lgv.z + lbv.z;
        y.w = (x0.w - mu) * rs * lgv.w + lbv.w;
        y.x = (y.x >= 0.f) ? y.x : pav.x * y.x;
        y.y = (y.y >= 0.f) ? y.y : pav.y * y.y;
        y.z = (y.z >= 0.f) ? y.z : pav.z * y.z;
        y.w = (y.w >= 0.f) ? y.w : pav.w * y.w;
        *(float4*)&u[d * H + 4 * q] = y;
    }
}

// ---------------- GENConv softmax aggregation (vectorized gather) ----------------

__global__ void k_gen(const int* __restrict__ rowptr, const int* __restrict__ csr,
                      const float* __restrict__ u, const float* __restrict__ tptr,
                      int li, float* __restrict__ ua) {
    int d = (blockIdx.x * blockDim.x + threadIdx.x) >> 6;
    int lane = threadIdx.x & 63;
    if (d >= NND) return;
    int q = lane & 15, eg = lane >> 4;
    float t = tptr[li];
    int beg = rowptr[d], end = rowptr[d + 1];
    float4 s4 = {0.f, 0.f, 0.f, 0.f}, n4 = {0.f, 0.f, 0.f, 0.f};
    for (int i0 = beg; i0 < end; i0 += 64) {
        int idx = i0 + lane;
        int csrv = (idx < end) ? csr[idx] : 0;
        int chunk = min(64, end - i0);
        for (int j = 0; j < chunk; j += 4) {
            int e_rel = j + eg;
            int s = __shfl(csrv, e_rel, 64);
            if (i0 + e_rel < end) {
                float4 uv = *(const float4*)&u[s * H + 4 * q];
                float m0 = fmaxf(uv.x, 0.f) + EPS_MSG;
                float m1 = fmaxf(uv.y, 0.f) + EPS_MSG;
                float m2 = fmaxf(uv.z, 0.f) + EPS_MSG;
                float m3 = fmaxf(uv.w, 0.f) + EPS_MSG;
                float e0 = __expf(m0 * t - 8.f);
                float e1 = __expf(m1 * t - 8.f);
                float e2 = __expf(m2 * t - 8.f);
                float e3 = __expf(m3 * t - 8.f);
                s4.x += e0; s4.y += e1; s4.z += e2; s4.w += e3;
                n4.x += m0 * e0; n4.y += m1 * e1; n4.z += m2 * e2; n4.w += m3 * e3;
            }
        }
    }
#pragma unroll
    for (int off = 16; off <= 32; off <<= 1) {
        s4.x += __shfl_xor(s4.x, off, 64); s4.y += __shfl_xor(s4.y, off, 64);
        s4.z += __shfl_xor(s4.z, off, 64); s4.w += __shfl_xor(s4.w, off, 64);
        n4.x += __shfl_xor(n4.x, off, 64); n4.y += __shfl_xor(n4.y, off, 64);
        n4.z += __shfl_xor(n4.z, off, 64); n4.w += __shfl_xor(n4.w, off, 64);
    }
    if (eg == 0) {
        float4 us = *(const float4*)&u[d * H + 4 * q];
        float4 o;
        o.x = us.x + ((s4.x > 0.f) ? n4.x / s4.x : 0.f);
        o.y = us.y + ((s4.y > 0.f) ? n4.y / s4.y : 0.f);
        o.z = us.z + ((s4.z > 0.f) ? n4.z / s4.z : 0.f);
        o.w = us.w + ((s4.w > 0.f) ? n4.w / s4.w : 0.f);
        *(float4*)&ua[d * H + 4 * q] = o;
    }
}

// ---------------- fused MLP (register-tiled GEMM) ----------------
// 64 nodes/block. Phase 1: thread tile 8n x 4j (acc 8xfloat4), per-k:
// 2 LDS b128 + 1 global float4 (W1) + 32 FMA -> VALU-bound.
// Phase 2: thread tile 4n x 4c, per-j: 1 LDS b128 + 1 float4 (W2) + 16 FMA.

__global__ void __launch_bounds__(256)
k_mlp(const float* __restrict__ ua,
      const float* __restrict__ W1, const float* __restrict__ b1,
      const float* __restrict__ bng, const float* __restrict__ bnb,
      const float* __restrict__ W2, const float* __restrict__ b2,
      float* __restrict__ xc, int slice,
      const float* __restrict__ lg, const float* __restrict__ lb,
      const float* __restrict__ pa, float* __restrict__ u_next, int do_ln) {
    __shared__ __align__(16) float u_t[64][MT + 4];    // [k][node]
    __shared__ __align__(16) float z1_t[128][MT + 4];  // [j][node]
    int t = threadIdx.x;
    int nb = blockIdx.x * MT;

    // stage ua tile transposed: thread -> node t>>2, c-range (t&3)*16
    {
        int n = t >> 2, c0 = (t & 3) * 16;
        int gn = nb + n;
#pragma unroll
        for (int i = 0; i < 4; i++) {
            float4 v = {0.f, 0.f, 0.f, 0.f};
            if (gn < NND) v = *(const float4*)&ua[gn * H + c0 + 4 * i];
            u_t[c0 + 4 * i + 0][n] = v.x;
            u_t[c0 + 4 * i + 1][n] = v.y;
            u_t[c0 + 4 * i + 2][n] = v.z;
            u_t[c0 + 4 * i + 3][n] = v.w;
        }
    }
    __syncthreads();

    // phase 1
    {
        int jg = t & 31;  int j0 = jg * 4;     // 4 j's
        int ng = t >> 5;  int n0 = ng * 8;     // 8 nodes
        float4 acc[8];
#pragma unroll
        for (int m = 0; m < 8; m++) acc[m] = {0.f, 0.f, 0.f, 0.f};
        for (int k = 0; k < 64; k++) {
            float4 w = *(const float4*)&W1[k * H2 + j0];
            float4 a0 = *(const float4*)&u_t[k][n0];
            float4 a1 = *(const float4*)&u_t[k][n0 + 4];
            acc[0].x += a0.x * w.x; acc[0].y += a0.x * w.y; acc[0].z += a0.x * w.z; acc[0].w += a0.x * w.w;
            acc[1].x += a0.y * w.x; acc[1].y += a0.y * w.y; acc[1].z += a0.y * w.z; acc[1].w += a0.y * w.w;
            acc[2].x += a0.z * w.x; acc[2].y += a0.z * w.y; acc[2].z += a0.z * w.z; acc[2].w += a0.z * w.w;
            acc[3].x += a0.w * w.x; acc[3].y += a0.w * w.y; acc[3].z += a0.w * w.z; acc[3].w += a0.w * w.w;
            acc[4].x += a1.x * w.x; acc[4].y += a1.x * w.y; acc[4].z += a1.x * w.z; acc[4].w += a1.x * w.w;
            acc[5].x += a1.y * w.x; acc[5].y += a1.y * w.y; acc[5].z += a1.y * w.z; acc[5].w += a1.y * w.w;
            acc[6].x += a1.z * w.x; acc[6].y += a1.z * w.y; acc[6].z += a1.z * w.z; acc[6].w += a1.z * w.w;
            acc[7].x += a1.w * w.x; acc[7].y += a1.w * w.y; acc[7].z += a1.w * w.z; acc[7].w += a1.w * w.w;
        }
        float4 b1v = *(const float4*)&b1[j0];
        float4 gv  = *(const float4*)&bng[j0];
        float4 bbv = *(const float4*)&bnb[j0];
        float bns = rsqrtf(1.f + EPS_BN);
        float4 bs = {gv.x * bns, gv.y * bns, gv.z * bns, gv.w * bns};
        // z1_t[j0+a][n0..n0+8] : transpose acc in registers, float4 writes
#pragma unroll
        for (int a = 0; a < 4; a++) {
            float va[8];
#pragma unroll
            for (int m = 0; m < 8; m++) {
                float z = (a == 0) ? acc[m].x : (a == 1) ? acc[m].y : (a == 2) ? acc[m].z : acc[m].w;
                float bv = (a == 0) ? b1v.x : (a == 1) ? b1v.y : (a == 2) ? b1v.z : b1v.w;
                float sv = (a == 0) ? bs.x : (a == 1) ? bs.y : (a == 2) ? bs.z : bs.w;
                float ov = (a == 0) ? bbv.x : (a == 1) ? bbv.y : (a == 2) ? bbv.z : bbv.w;
                va[m] = fmaxf((z + bv) * sv + ov, 0.f);
            }
            float4 w0 = {va[0], va[1], va[2], va[3]};
            float4 w1v = {va[4], va[5], va[6], va[7]};
            *(float4*)&z1_t[j0 + a][n0] = w0;
            *(float4*)&z1_t[j0 + a][n0 + 4] = w1v;
        }
    }
    __syncthreads();

    // phase 2
    {
        int cg = t & 15;  int c0 = cg * 4;     // 4 c's
        int ng = t >> 4;  int n0 = ng * 4;     // 4 nodes
        float4 acc[4];
#pragma unroll
        for (int m = 0; m < 4; m++) acc[m] = {0.f, 0.f, 0.f, 0.f};
        for (int j = 0; j < 128; j++) {
            float4 w = *(const float4*)&W2[j * H + c0];
            float4 z = *(const float4*)&z1_t[j][n0];
            acc[0].x += z.x * w.x; acc[0].y += z.x * w.y; acc[0].z += z.x * w.z; acc[0].w += z.x * w.w;
            acc[1].x += z.y * w.x; acc[1].y += z.y * w.y; acc[1].z += z.y * w.z; acc[1].w += z.y * w.w;
            acc[2].x += z.z * w.x; acc[2].y += z.z * w.y; acc[2].z += z.z * w.z; acc[2].w += z.z * w.w;
            acc[3].x += z.w * w.x; acc[3].y += z.w * w.y; acc[3].z += z.w * w.z; acc[3].w += z.w * w.w;
        }
        float4 b2v = *(const float4*)&b2[c0];
        float4 lgv = {0,0,0,0}, lbv = {0,0,0,0}, pav = {0,0,0,0};
        if (do_ln) {
            lgv = *(const float4*)&lg[c0];
            lbv = *(const float4*)&lb[c0];
            pav = *(const float4*)&pa[c0];
        }
#pragma unroll
        for (int m = 0; m < 4; m++) {
            int gn = nb + n0 + m;
            float4 v = {0.f, 0.f, 0.f, 0.f};
            if (gn < NND) {
                float4 r = *(const float4*)&xc[(size_t)gn * H4 + slice * H + c0];
                v.x = r.x + acc[m].x + b2v.x;
                v.y = r.y + acc[m].y + b2v.y;
                v.z = r.z + acc[m].z + b2v.z;
                v.w = r.w + acc[m].w + b2v.w;
                *(float4*)&xc[(size_t)gn * H4 + (slice + 1) * H + c0] = v;
            }
            if (do_ln) {
                float sum = (v.x + v.y) + (v.z + v.w);
                float sq  = (v.x * v.x + v.y * v.y) + (v.z * v.z + v.w * v.w);
#pragma unroll
                for (int off = 1; off <= 8; off <<= 1) {
                    sum += __shfl_xor(sum, off, 64);
                    sq  += __shfl_xor(sq,  off, 64);
                }
                float mu  = sum * (1.f / H);
                float var = sq * (1.f / H) - mu * mu;
                float rs = rsqrtf(var + EPS_BN);
                float4 y;
                y.x = (v.x - mu) * rs * lgv.x + lbv.x;
                y.y = (v.y - mu) * rs * lgv.y + lbv.y;
                y.z = (v.z - mu) * rs * lgv.z + lbv.z;
                y.w = (v.w - mu) * rs * lgv.w + lbv.w;
                y.x = (y.x >= 0.f) ? y.x : pav.x * y.x;
                y.y = (y.y >= 0.f) ? y.y : pav.y * y.y;
                y.z = (y.z >= 0.f) ? y.z : pav.z * y.z;
                y.w = (y.w >= 0.f) ? y.w : pav.w * y.w;
                if (gn < NND) *(float4*)&u_next[gn * H + c0] = y;
            }
        }
    }
}

// ---------------- pooling + readout ----------------

__global__ void k_gbounds(const int* __restrict__ batch, int* __restrict__ gstart) {
    int g = threadIdx.x + blockIdx.x * blockDim.x;
    if (g > NG) return;
    int lo = 0, hi = NND;
    while (lo < hi) { int mid = (lo + hi) >> 1; if (batch[mid] < g) lo = mid + 1; else hi = mid; }
    gstart[g] = lo;
}

__global__ void __launch_bounds__(256)
k_pool1(const float* __restrict__ xc, const int* __restrict__ gstart,
        float* __restrict__ psum_p, float* __restrict__ pmax_p) {
    __shared__ float4 ssum[256];
    __shared__ float4 smax[256];
    int b = blockIdx.x;
    int g = b >> 3, k = b & (PC - 1);
    int t = threadIdx.x;
    int start = gstart[g], end = gstart[g + 1];
    int len = end - start;
    int c0 = start + (len * k) / PC;
    int c1 = start + (len * (k + 1)) / PC;
    int q = t & 63, sub = t >> 6;
    float4 sum = {0.f, 0.f, 0.f, 0.f};
    float4 mx = {-INFINITY, -INFINITY, -INFINITY, -INFINITY};
    for (int n = c0 + sub; n < c1; n += 4) {
        float4 v = *(const float4*)&xc[(size_t)n * H4 + 4 * q];
        sum.x += v.x; sum.y += v.y; sum.z += v.z; sum.w += v.w;
        mx.x = fmaxf(mx.x, v.x); mx.y = fmaxf(mx.y, v.y);
        mx.z = fmaxf(mx.z, v.z); mx.w = fmaxf(mx.w, v.w);
    }
    ssum[t] = sum; smax[t] = mx;
    __syncthreads();
    if (t < 64) {
        float4 s0 = ssum[t], s1 = ssum[t + 64], s2 = ssum[t + 128], s3 = ssum[t + 192];
        float4 m0 = smax[t], m1 = smax[t + 64], m2 = smax[t + 128], m3 = smax[t + 192];
        float4 S, M;
        S.x = (s0.x + s1.x) + (s2.x + s3.x);
        S.y = (s0.y + s1.y) + (s2.y + s3.y);
        S.z = (s0.z + s1.z) + (s2.z + s3.z);
        S.w = (s0.w + s1.w) + (s2.w + s3.w);
        M.x = fmaxf(fmaxf(m0.x, m1.x), fmaxf(m2.x, m3.x));
        M.y = fmaxf(fmaxf(m0.y, m1.y), fmaxf(m2.y, m3.y));
        M.z = fmaxf(fmaxf(m0.z, m1.z), fmaxf(m2.z, m3.z));
        M.w = fmaxf(fmaxf(m0.w, m1.w), fmaxf(m2.w, m3.w));
        *(float4*)&psum_p[(size_t)b * H4 + 4 * q] = S;
        *(float4*)&pmax_p[(size_t)b * H4 + 4 * q] = M;
    }
}

__global__ void __launch_bounds__(256)
k_readout(const float* __restrict__ psum_p, const float* __restrict__ pmax_p,
          const int* __restrict__ gstart,
          const float* __restrict__ W1, const float* __restrict__ b1,
          const float* __restrict__ W2, const float* __restrict__ b2,
          const float* __restrict__ Wo, const float* __restrict__ bo,
          float* __restrict__ out) {
    __shared__ float p0_l[H8];
    __shared__ float p1part[2][H2];
    __shared__ float p1_l[H2];
    __shared__ float p2part[4][H];
    __shared__ float p2_l[H];
    int g = blockIdx.x;
    int t = threadIdx.x;

    {
        float s = 0.f, m = -INFINITY;
#pragma unroll
        for (int k = 0; k < PC; k++) {
            s += psum_p[(size_t)(g * PC + k) * H4 + t];
            m = fmaxf(m, pmax_p[(size_t)(g * PC + k) * H4 + t]);
        }
        int cnt = gstart[g + 1] - gstart[g];
        p0_l[t] = s / fmaxf((float)cnt, 1.f);
        p0_l[H4 + t] = (cnt > 0) ? m : 0.f;
    }
    __syncthreads();

    {
        int j = t & 127, h = t >> 7;
        float acc = 0.f;
        int k0 = h * 256;
        for (int k = 0; k < 256; k++) acc += p0_l[k0 + k] * W1[(k0 + k) * H2 + j];
        p1part[h][j] = acc;
    }
    __syncthreads();
    if (t < H2) p1_l[t] = fmaxf(p1part[0][t] + p1part[1][t] + b1[t], 0.f);
    __syncthreads();

    {
        int c = t & 63, h = t >> 6;
        float acc = 0.f;
        int k0 = h * 32;
        for (int k = 0; k < 32; k++) acc += p1_l[k0 + k] * W2[(k0 + k) * H + c];
        p2part[h][c] = acc;
    }
    __syncthreads();
    if (t < H) p2_l[t] = fmaxf(((p2part[0][t] + p2part[1][t]) + (p2part[2][t] + p2part[3][t])) + b2[t], 0.f);
    __syncthreads();

    if (t < 64) {
        float v = p2_l[t] * Wo[t];
#pragma unroll
        for (int off = 32; off >= 1; off >>= 1) v += __shfl_xor(v, off, 64);
        if (t == 0) out[g] = v + bo[0];
    }
}

extern "C" void kernel_launch(void* const* d_in, const int* in_sizes, int n_in,
                              void* d_out, int out_size, void* d_ws, size_t ws_size,
                              hipStream_t stream) {
    const float* x       = (const float*)d_in[0];
    const int*   ei      = (const int*)d_in[1];
    const int*   batch   = (const int*)d_in[2];
    const float* conv1_W = (const float*)d_in[3];
    const float* conv1_b = (const float*)d_in[4];
    const float* bn1_g   = (const float*)d_in[5];
    const float* bn1_b   = (const float*)d_in[6];
    const float* ln_g    = (const float*)d_in[7];
    const float* ln_b    = (const float*)d_in[8];
    const float* prelu_a = (const float*)d_in[9];
    const float* gen_t   = (const float*)d_in[10];
    const float* mlp_W1  = (const float*)d_in[11];
    const float* mlp_b1  = (const float*)d_in[12];
    const float* mlp_bng = (const float*)d_in[13];
    const float* mlp_bnb = (const float*)d_in[14];
    const float* mlp_W2  = (const float*)d_in[15];
    const float* mlp_b2  = (const float*)d_in[16];
    const float* lin1_W  = (const float*)d_in[17];
    const float* lin1_b  = (const float*)d_in[18];
    const float* lin2_W  = (const float*)d_in[19];
    const float* lin2_b  = (const float*)d_in[20];
    const float* out_W   = (const float*)d_in[21];
    const float* out_b   = (const float*)d_in[22];
    float* out = (float*)d_out;

    float* ws   = (float*)d_ws;
    float* xc   = ws;                          // NND*H4
    float* u    = xc + (size_t)NND * H4;       // NND*H
    float* ua   = u + (size_t)NND * H;         // NND*H (t0 aliases)
    float* t0   = ua;
    float* dinv = ua + (size_t)NND * H;        // NND
    int* rowptr = (int*)(dinv + NND);          // NND+1
    int* next   = rowptr + (NND + 1);          // NND
    int* counts = next + NND;                  // NND
    int* bsum   = counts + NND;                // NB
    int* boff   = bsum + NB;                   // NB
    int* csr    = boff + NB;                   // NE
    float* psum_p = (float*)(csr + NE);        // NG*PC*H4
    float* pmax_p = psum_p + (size_t)NG * PC * H4;
    int* gstart = (int*)(pmax_p + (size_t)NG * PC * H4);

    const int B = 256;
    const int gN   = (NND + B - 1) / B;
    const int gNH  = (NND * H) / B;
    const int gMLP = (NND + MT - 1) / MT;   // 782
    const int gEP  = NXP * ECH;

    // ---- CSR build ----
    k_zero_counts<<<gN, B, 0, stream>>>(counts);
    k_count_p<<<gEP, B, 0, stream>>>(ei, counts);
    k_scan1<<<NB, B, 0, stream>>>(counts, rowptr, bsum);
    k_scan2<<<1, B, 0, stream>>>(bsum, boff, rowptr);
    k_scan3<<<NB, B, 0, stream>>>(boff, counts, rowptr, next, dinv);
    k_scatter_p<<<gEP, B, 0, stream>>>(ei, next, csr);
    k_gbounds<<<2, 256, 0, stream>>>(batch, gstart);

    // ---- GCNConv + LN0/PReLU0 ----
    k_conv1<<<gNH, B, 0, stream>>>(x, conv1_W, t0);
    k_gcn<<<gNH, B, 0, stream>>>(rowptr, csr, t0, dinv, conv1_b, bn1_g, bn1_b,
                                 ln_g, ln_b, prelu_a, xc, u);

    // ---- DeepGCN layers ----
    for (int i = 0; i < 3; i++) {
        k_gen<<<gNH, B, 0, stream>>>(rowptr, csr, u, gen_t, i, ua);
        int do_ln = (i < 2) ? 1 : 0;
        k_mlp<<<gMLP, B, 0, stream>>>(ua,
                                      mlp_W1 + (size_t)i * H * H2, mlp_b1 + i * H2,
                                      mlp_bng + i * H2, mlp_bnb + i * H2,
                                      mlp_W2 + (size_t)i * H2 * H, mlp_b2 + i * H,
                                      xc, i,
                                      ln_g + (i + 1) * H, ln_b + (i + 1) * H,
                                      prelu_a + (i + 1) * H, u, do_ln);
    }

    // ---- pooling + readout ----
    k_pool1<<<NG * PC, B, 0, stream>>>(xc, gstart, psum_p, pmax_p);
    k_readout<<<NG, B, 0, stream>>>(psum_p, pmax_p, gstart,
                                    lin1_W, lin1_b, lin2_W, lin2_b, out_W, out_b, out);
}

// Round 7
// 479.128 us; speedup vs baseline: 7.3459x; 1.1683x over previous
//
#include <hip/hip_runtime.h>
#include <math.h>

#define NND 50000
#define NE  1200000
#define NG  256
#define H   64
#define H2  128
#define H4  256
#define H8  512
#define FIN 5
#define EPS_BN 1e-5f
#define EPS_MSG 1e-7f
#define NB 196          // ceil(NND/256)
#define NXP 8           // XCD partitions
#define DPART 6250      // NND / NXP
#define ECH 4688        // ceil(NE/256)
#define PC 8            // pool chunks per graph
#define MT 64           // nodes per mlp block

typedef _Float16 half8 __attribute__((ext_vector_type(8)));
typedef float floatx4 __attribute__((ext_vector_type(4)));

// ---------------- CSR build (by dst), XCD-partitioned ----------------

__global__ void k_zero_counts(int* counts) {
    int n = blockIdx.x * blockDim.x + threadIdx.x;
    if (n < NND) counts[n] = 0;
}

__global__ void k_count_p(const int* __restrict__ ei, int* counts) {
    int b = blockIdx.x;
    int g = b & (NXP - 1);
    int e = (b >> 3) * 256 + threadIdx.x;
    if (e >= NE) return;
    int d = ei[NE + e];
    if ((unsigned)(d - g * DPART) < (unsigned)DPART) atomicAdd(&counts[d], 1);
}

__global__ void k_scan1(const int* __restrict__ counts, int* __restrict__ rowptr,
                        int* __restrict__ bsum) {
    __shared__ int wsum[4];
    int b = blockIdx.x, t = threadIdx.x;
    int i = b * 256 + t;
    int v = (i < NND) ? counts[i] : 0;
    int lane = t & 63, wid = t >> 6;
    int sv = v;
#pragma unroll
    for (int off = 1; off < 64; off <<= 1) {
        int x = __shfl_up(sv, off, 64);
        if (lane >= off) sv += x;
    }
    if (lane == 63) wsum[wid] = sv;
    __syncthreads();
    int woff = 0;
    for (int w = 0; w < wid; w++) woff += wsum[w];
    int inc = woff + sv;
    if (i < NND) rowptr[i + 1] = inc;
    if (t == 255) bsum[b] = inc;
}

__global__ void k_scan2(const int* __restrict__ bsum, int* __restrict__ boff,
                        int* __restrict__ rowptr) {
    __shared__ int wsum[4];
    int t = threadIdx.x;
    int v = (t < NB) ? bsum[t] : 0;
    int lane = t & 63, wid = t >> 6;
    int sv = v;
#pragma unroll
    for (int off = 1; off < 64; off <<= 1) {
        int x = __shfl_up(sv, off, 64);
        if (lane >= off) sv += x;
    }
    if (lane == 63) wsum[wid] = sv;
    __syncthreads();
    int woff = 0;
    for (int w = 0; w < wid; w++) woff += wsum[w];
    if (t < NB) boff[t] = woff + sv - v;
    if (t == 0) rowptr[0] = 0;
}

__global__ void k_scan3(const int* __restrict__ boff, const int* __restrict__ counts,
                        int* __restrict__ rowptr, int* __restrict__ next,
                        float* __restrict__ dinv) {
    int i = blockIdx.x * 256 + threadIdx.x;
    if (i >= NND) return;
    int r = rowptr[i + 1] + boff[i >> 8];
    rowptr[i + 1] = r;
    next[i] = r - counts[i];
    dinv[i] = rsqrtf((float)counts[i] + 1.0f);
}

__global__ void k_scatter_p(const int* __restrict__ ei, int* next, int* csr) {
    int b = blockIdx.x;
    int g = b & (NXP - 1);
    int e = (b >> 3) * 256 + threadIdx.x;
    if (e >= NE) return;
    int d = ei[NE + e];
    if ((unsigned)(d - g * DPART) < (unsigned)DPART) {
        int pos = atomicAdd(&next[d], 1);
        csr[pos] = ei[e];
    }
}

// ---------------- weight pre-swizzle into MFMA B-frag layout ----------------
// w1f[layer][jt=8][kf=2][lane=64][i=8] = W1[layer][k=kf*32+(lane>>4)*8+i][j=jt*16+(lane&15)]
// w2f[layer][ct=4][k2f=4][lane=64][i=8] = W2[layer][k=k2f*32+(lane>>4)*8+i][c=ct*16+(lane&15)]

__global__ void k_wswz(const float* __restrict__ W1, const float* __restrict__ W2,
                       _Float16* __restrict__ w1f, _Float16* __restrict__ w2f) {
    int t = blockIdx.x * blockDim.x + threadIdx.x;   // 3*16*64 = 3072
    if (t >= 3 * 16 * 64) return;
    int lane = t & 63, fr = (t >> 6) & 15, l = t >> 10;
    {
        int jt = fr >> 1, kf = fr & 1;
        int j = jt * 16 + (lane & 15);
        int k0 = kf * 32 + (lane >> 4) * 8;
#pragma unroll
        for (int i = 0; i < 8; i++)
            w1f[(((size_t)l * 16 + jt * 2 + kf) * 64 + lane) * 8 + i] =
                (_Float16)W1[(size_t)l * H * H2 + (k0 + i) * H2 + j];
    }
    {
        int ct = fr >> 2, k2f = fr & 3;
        int c = ct * 16 + (lane & 15);
        int k0 = k2f * 32 + (lane >> 4) * 8;
#pragma unroll
        for (int i = 0; i < 8; i++)
            w2f[(((size_t)l * 16 + ct * 4 + k2f) * 64 + lane) * 8 + i] =
                (_Float16)W2[(size_t)l * H2 * H + (k0 + i) * H + c];
    }
}

// ---------------- GCNConv (fused gather + BN + ReLU + LN0 + PReLU0) ----------------

__global__ void k_conv1(const float* __restrict__ x, const float* __restrict__ W,
                        float* __restrict__ t0) {
    int tid = blockIdx.x * blockDim.x + threadIdx.x;
    if (tid >= NND * H) return;
    int n = tid >> 6, c = tid & 63;
    float acc = 0.f;
#pragma unroll
    for (int k = 0; k < FIN; k++) acc += x[n * FIN + k] * W[k * H + c];
    t0[n * H + c] = acc;
}

__global__ void k_gcn(const int* __restrict__ rowptr, const int* __restrict__ csr,
                      const float* __restrict__ t0, const float* __restrict__ dinv,
                      const float* __restrict__ cb, const float* __restrict__ bg,
                      const float* __restrict__ bb,
                      const float* __restrict__ lg, const float* __restrict__ lb,
                      const float* __restrict__ pa,
                      float* __restrict__ xc, float* __restrict__ u) {
    int d = (blockIdx.x * blockDim.x + threadIdx.x) >> 6;
    int lane = threadIdx.x & 63;
    if (d >= NND) return;
    int q = lane & 15, eg = lane >> 4;
    int beg = rowptr[d], end = rowptr[d + 1];
    float4 acc = {0.f, 0.f, 0.f, 0.f};
    for (int i0 = beg; i0 < end; i0 += 64) {
        int idx = i0 + lane;
        int csrv = 0; float dvv = 0.f;
        if (idx < end) { csrv = csr[idx]; dvv = dinv[csrv]; }
        int chunk = min(64, end - i0);
        for (int j = 0; j < chunk; j += 4) {
            int e_rel = j + eg;
            int s  = __shfl(csrv, e_rel, 64);
            float dv = __shfl(dvv, e_rel, 64);
            if (i0 + e_rel < end) {
                float4 tv = *(const float4*)&t0[s * H + 4 * q];
                acc.x += tv.x * dv; acc.y += tv.y * dv;
                acc.z += tv.z * dv; acc.w += tv.w * dv;
            }
        }
    }
#pragma unroll
    for (int off = 16; off <= 32; off <<= 1) {
        acc.x += __shfl_xor(acc.x, off, 64);
        acc.y += __shfl_xor(acc.y, off, 64);
        acc.z += __shfl_xor(acc.z, off, 64);
        acc.w += __shfl_xor(acc.w, off, 64);
    }
    if (eg == 0) {
        float dd = dinv[d];
        float4 ts = *(const float4*)&t0[d * H + 4 * q];
        float4 cbv = *(const float4*)&cb[4 * q];
        float4 bgv = *(const float4*)&bg[4 * q];
        float4 bbv = *(const float4*)&bb[4 * q];
        float bns = rsqrtf(1.f + EPS_BN);
        float4 x0;
        x0.x = fmaxf((acc.x * dd + ts.x * dd * dd + cbv.x) * (bgv.x * bns) + bbv.x, 0.f);
        x0.y = fmaxf((acc.y * dd + ts.y * dd * dd + cbv.y) * (bgv.y * bns) + bbv.y, 0.f);
        x0.z = fmaxf((acc.z * dd + ts.z * dd * dd + cbv.z) * (bgv.z * bns) + bbv.z, 0.f);
        x0.w = fmaxf((acc.w * dd + ts.w * dd * dd + cbv.w) * (bgv.w * bns) + bbv.w, 0.f);
        *(float4*)&xc[(size_t)d * H4 + 4 * q] = x0;
        float sum = (x0.x + x0.y) + (x0.z + x0.w);
        float sq  = (x0.x * x0.x + x0.y * x0.y) + (x0.z * x0.z + x0.w * x0.w);
#pragma unroll
        for (int off = 1; off <= 8; off <<= 1) {
            sum += __shfl_xor(sum, off, 64);
            sq  += __shfl_xor(sq,  off, 64);
        }
        float mu  = sum * (1.f / H);
        float var = sq * (1.f / H) - mu * mu;
        float rs = rsqrtf(var + EPS_BN);
        float4 lgv = *(const float4*)&lg[4 * q];
        float4 lbv = *(const float4*)&lb[4 * q];
        float4 pav = *(const float4*)&pa[4 * q];
        float4 y;
        y.x = (x0.x - mu) * rs * lgv.x + lbv.x;
        y.y = (x0.y - mu) * rs * lgv.y + lbv.y;
        y.z = (x0.z - mu) * rs * lgv.z + lbv.z;
        y.w = (x0.w - mu) * rs * lgv.w + lbv.w;
        y.x = (y.x >= 0.f) ? y.x : pav.x * y.x;
        y.y = (y.y >= 0.f) ? y.y : pav.y * y.y;
        y.z = (y.z >= 0.f) ? y.z : pav.z * y.z;
        y.w = (y.w >= 0.f) ? y.w : pav.w * y.w;
        *(float4*)&u[d * H + 4 * q] = y;
    }
}

// ---------------- GENConv softmax aggregation (vectorized gather) ----------------

__global__ void k_gen(const int* __restrict__ rowptr, const int* __restrict__ csr,
                      const float* __restrict__ u, const float* __restrict__ tptr,
                      int li, float* __restrict__ ua) {
    int d = (blockIdx.x * blockDim.x + threadIdx.x) >> 6;
    int lane = threadIdx.x & 63;
    if (d >= NND) return;
    int q = lane & 15, eg = lane >> 4;
    float t = tptr[li];
    int beg = rowptr[d], end = rowptr[d + 1];
    float4 s4 = {0.f, 0.f, 0.f, 0.f}, n4 = {0.f, 0.f, 0.f, 0.f};
    for (int i0 = beg; i0 < end; i0 += 64) {
        int idx = i0 + lane;
        int csrv = (idx < end) ? csr[idx] : 0;
        int chunk = min(64, end - i0);
        for (int j = 0; j < chunk; j += 4) {
            int e_rel = j + eg;
            int s = __shfl(csrv, e_rel, 64);
            if (i0 + e_rel < end) {
                float4 uv = *(const float4*)&u[s * H + 4 * q];
                float m0 = fmaxf(uv.x, 0.f) + EPS_MSG;
                float m1 = fmaxf(uv.y, 0.f) + EPS_MSG;
                float m2 = fmaxf(uv.z, 0.f) + EPS_MSG;
                float m3 = fmaxf(uv.w, 0.f) + EPS_MSG;
                float e0 = __expf(m0 * t - 8.f);
                float e1 = __expf(m1 * t - 8.f);
                float e2 = __expf(m2 * t - 8.f);
                float e3 = __expf(m3 * t - 8.f);
                s4.x += e0; s4.y += e1; s4.z += e2; s4.w += e3;
                n4.x += m0 * e0; n4.y += m1 * e1; n4.z += m2 * e2; n4.w += m3 * e3;
            }
        }
    }
#pragma unroll
    for (int off = 16; off <= 32; off <<= 1) {
        s4.x += __shfl_xor(s4.x, off, 64); s4.y += __shfl_xor(s4.y, off, 64);
        s4.z += __shfl_xor(s4.z, off, 64); s4.w += __shfl_xor(s4.w, off, 64);
        n4.x += __shfl_xor(n4.x, off, 64); n4.y += __shfl_xor(n4.y, off, 64);
        n4.z += __shfl_xor(n4.z, off, 64); n4.w += __shfl_xor(n4.w, off, 64);
    }
    if (eg == 0) {
        float4 us = *(const float4*)&u[d * H + 4 * q];
        float4 o;
        o.x = us.x + ((s4.x > 0.f) ? n4.x / s4.x : 0.f);
        o.y = us.y + ((s4.y > 0.f) ? n4.y / s4.y : 0.f);
        o.z = us.z + ((s4.z > 0.f) ? n4.z / s4.z : 0.f);
        o.w = us.w + ((s4.w > 0.f) ? n4.w / s4.w : 0.f);
        *(float4*)&ua[d * H + 4 * q] = o;
    }
}

// ---------------- fused MLP via MFMA (f16 inputs, f32 accumulate) ----------------
// 64 nodes/block, wave w owns nodes [nb+16w, nb+16w+16): GEMM1 (K=64, 8 j-tiles,
// 16 MFMA) -> BN/ReLU -> LDS (A-frag layout) -> GEMM2 (K=128, 4 c-tiles, 16 MFMA)
// -> residual + optional LN/PReLU. All LDS traffic is intra-wave: no barriers.

__global__ void __launch_bounds__(256)
k_mlp(const float* __restrict__ ua,
      const _Float16* __restrict__ w1f, const _Float16* __restrict__ w2f,
      const float* __restrict__ b1,
      const float* __restrict__ bng, const float* __restrict__ bnb,
      const float* __restrict__ b2,
      float* __restrict__ xc, int slice,
      const float* __restrict__ lg, const float* __restrict__ lb,
      const float* __restrict__ pa, float* __restrict__ u_next, int do_ln) {
    __shared__ _Float16 a1[4][2][64][8];   // 8 KB  [mtile][kf][lane][i]
    __shared__ _Float16 a2[4][4][64][8];   // 16 KB [mtile][k2f][lane][i]
    int t = threadIdx.x;
    int w = t >> 6, l = t & 63;
    int nb = blockIdx.x * MT;
    int c_in = l & 15, quad = l >> 4;
    bool wvalid = (nb + 16 * w) < NND;

    // ---- stage ua -> a1 (f16, A-frag layout); thread t: node t>>2, k-range (t&3)*16
    {
        int n = t >> 2;
        int k0 = (t & 3) * 16;
        int gn = nb + n;
        float4 v0 = {0,0,0,0}, v1 = v0, v2 = v0, v3 = v0;
        if (gn < NND) {
            v0 = *(const float4*)&ua[gn * H + k0];
            v1 = *(const float4*)&ua[gn * H + k0 + 4];
            v2 = *(const float4*)&ua[gn * H + k0 + 8];
            v3 = *(const float4*)&ua[gn * H + k0 + 12];
        }
        int mt = n >> 4, kf = k0 >> 5, g0 = (k0 >> 3) & 3;
        half8 h0 = {(_Float16)v0.x, (_Float16)v0.y, (_Float16)v0.z, (_Float16)v0.w,
                    (_Float16)v1.x, (_Float16)v1.y, (_Float16)v1.z, (_Float16)v1.w};
        half8 h1 = {(_Float16)v2.x, (_Float16)v2.y, (_Float16)v2.z, (_Float16)v2.w,
                    (_Float16)v3.x, (_Float16)v3.y, (_Float16)v3.z, (_Float16)v3.w};
        *(half8*)&a1[mt][kf][(n & 15) + 16 * g0][0] = h0;
        *(half8*)&a1[mt][kf][(n & 15) + 16 * (g0 + 1)][0] = h1;
    }

    // ---- GEMM1: z1[16n x 128j] ----
    floatx4 acc[8];
#pragma unroll
    for (int jt = 0; jt < 8; jt++) acc[jt] = (floatx4){0.f, 0.f, 0.f, 0.f};
    half8 af0 = *(half8*)&a1[w][0][l][0];
    half8 af1 = *(half8*)&a1[w][1][l][0];
#pragma unroll
    for (int jt = 0; jt < 8; jt++) {
        half8 bf0 = *(const half8*)&w1f[((size_t)(jt * 2 + 0) * 64 + l) * 8];
        half8 bf1 = *(const half8*)&w1f[((size_t)(jt * 2 + 1) * 64 + l) * 8];
        acc[jt] = __builtin_amdgcn_mfma_f32_16x16x32_f16(af0, bf0, acc[jt], 0, 0, 0);
        acc[jt] = __builtin_amdgcn_mfma_f32_16x16x32_f16(af1, bf1, acc[jt], 0, 0, 0);
    }

    // ---- epilogue1: bias+BN+ReLU, scatter to a2 in A-frag layout ----
    {
        float bns = rsqrtf(1.f + EPS_BN);
#pragma unroll
        for (int jt = 0; jt < 8; jt++) {
            int j = jt * 16 + c_in;
            float b1v = b1[j], bsv = bng[j] * bns, bbv = bnb[j];
            int kf2 = jt >> 1;
            int lp = 16 * ((2 * jt + (c_in >> 3)) & 3);
            int ii = c_in & 7;
#pragma unroll
            for (int reg = 0; reg < 4; reg++) {
                float z = fmaxf((acc[jt][reg] + b1v) * bsv + bbv, 0.f);
                a2[w][kf2][quad * 4 + reg + lp][ii] = (_Float16)z;
            }
        }
    }

    // ---- GEMM2: z2[16n x 64c] ----
    floatx4 acc2[4];
#pragma unroll
    for (int ct = 0; ct < 4; ct++) acc2[ct] = (floatx4){0.f, 0.f, 0.f, 0.f};
    half8 a2f[4];
#pragma unroll
    for (int k2f = 0; k2f < 4; k2f++) a2f[k2f] = *(half8*)&a2[w][k2f][l][0];
#pragma unroll
    for (int ct = 0; ct < 4; ct++) {
#pragma unroll
        for (int k2f = 0; k2f < 4; k2f++) {
            half8 bfr = *(const half8*)&w2f[((size_t)(ct * 4 + k2f) * 64 + l) * 8];
            acc2[ct] = __builtin_amdgcn_mfma_f32_16x16x32_f16(a2f[k2f], bfr, acc2[ct], 0, 0, 0);
        }
    }

    // ---- epilogue2: residual write + optional LN/PReLU ----
    float vv[4][4];
#pragma unroll
    for (int ct = 0; ct < 4; ct++) {
        int c = ct * 16 + c_in;
        float b2v = b2[c];
#pragma unroll
        for (int reg = 0; reg < 4; reg++) {
            int node = nb + 16 * w + quad * 4 + reg;
            float v = 0.f;
            if (wvalid) {
                v = xc[(size_t)node * H4 + slice * H + c] + acc2[ct][reg] + b2v;
                xc[(size_t)node * H4 + (slice + 1) * H + c] = v;
            }
            vv[ct][reg] = v;
        }
    }
    if (do_ln) {
#pragma unroll
        for (int reg = 0; reg < 4; reg++) {
            float s = (vv[0][reg] + vv[1][reg]) + (vv[2][reg] + vv[3][reg]);
            float q = (vv[0][reg] * vv[0][reg] + vv[1][reg] * vv[1][reg]) +
                      (vv[2][reg] * vv[2][reg] + vv[3][reg] * vv[3][reg]);
#pragma unroll
            for (int off = 1; off <= 8; off <<= 1) {
                s += __shfl_xor(s, off, 64);
                q += __shfl_xor(q, off, 64);
            }
            float mu = s * (1.f / H);
            float var = q * (1.f / H) - mu * mu;
            float rs = rsqrtf(var + EPS_BN);
            int node = nb + 16 * w + quad * 4 + reg;
#pragma unroll
            for (int ct = 0; ct < 4; ct++) {
                int c = ct * 16 + c_in;
                float y = (vv[ct][reg] - mu) * rs * lg[c] + lb[c];
                y = (y >= 0.f) ? y : pa[c] * y;
                if (wvalid) u_next[node * H + c] = y;
            }
        }
    }
}

// ---------------- pooling + readout ----------------

__global__ void k_gbounds(const int* __restrict__ batch, int* __restrict__ gstart) {
    int g = threadIdx.x + blockIdx.x * blockDim.x;
    if (g > NG) return;
    int lo = 0, hi = NND;
    while (lo < hi) { int mid = (lo + hi) >> 1; if (batch[mid] < g) lo = mid + 1; else hi = mid; }
    gstart[g] = lo;
}

__global__ void __launch_bounds__(256)
k_pool1(const float* __restrict__ xc, const int* __restrict__ gstart,
        float* __restrict__ psum_p, float* __restrict__ pmax_p) {
    __shared__ float4 ssum[256];
    __shared__ float4 smax[256];
    int b = blockIdx.x;
    int g = b >> 3, k = b & (PC - 1);
    int t = threadIdx.x;
    int start = gstart[g], end = gstart[g + 1];
    int len = end - start;
    int c0 = start + (len * k) / PC;
    int c1 = start + (len * (k + 1)) / PC;
    int q = t & 63, sub = t >> 6;
    float4 sum = {0.f, 0.f, 0.f, 0.f};
    float4 mx = {-INFINITY, -INFINITY, -INFINITY, -INFINITY};
    for (int n = c0 + sub; n < c1; n += 4) {
        float4 v = *(const float4*)&xc[(size_t)n * H4 + 4 * q];
        sum.x += v.x; sum.y += v.y; sum.z += v.z; sum.w += v.w;
        mx.x = fmaxf(mx.x, v.x); mx.y = fmaxf(mx.y, v.y);
        mx.z = fmaxf(mx.z, v.z); mx.w = fmaxf(mx.w, v.w);
    }
    ssum[t] = sum; smax[t] = mx;
    __syncthreads();
    if (t < 64) {
        float4 s0 = ssum[t], s1 = ssum[t + 64], s2 = ssum[t + 128], s3 = ssum[t + 192];
        float4 m0 = smax[t], m1 = smax[t + 64], m2 = smax[t + 128], m3 = smax[t + 192];
        float4 S, M;
        S.x = (s0.x + s1.x) + (s2.x + s3.x);
        S.y = (s0.y + s1.y) + (s2.y + s3.y);
        S.z = (s0.z + s1.z) + (s2.z + s3.z);
        S.w = (s0.w + s1.w) + (s2.w + s3.w);
        M.x = fmaxf(fmaxf(m0.x, m1.x), fmaxf(m2.x, m3.x));
        M.y = fmaxf(fmaxf(m0.y, m1.y), fmaxf(m2.y, m3.y));
        M.z = fmaxf(fmaxf(m0.z, m1.z), fmaxf(m2.z, m3.z));
        M.w = fmaxf(fmaxf(m0.w, m1.w), fmaxf(m2.w, m3.w));
        *(float4*)&psum_p[(size_t)b * H4 + 4 * q] = S;
        *(float4*)&pmax_p[(size_t)b * H4 + 4 * q] = M;
    }
}

__global__ void __launch_bounds__(256)
k_readout(const float* __restrict__ psum_p, const float* __restrict__ pmax_p,
          const int* __restrict__ gstart,
          const float* __restrict__ W1, const float* __restrict__ b1,
          const float* __restrict__ W2, const float* __restrict__ b2,
          const float* __restrict__ Wo, const float* __restrict__ bo,
          float* __restrict__ out) {
    __shared__ float p0_l[H8];
    __shared__ float p1part[2][H2];
    __shared__ float p1_l[H2];
    __shared__ float p2part[4][H];
    __shared__ float p2_l[H];
    int g = blockIdx.x;
    int t = threadIdx.x;

    {
        float s = 0.f, m = -INFINITY;
#pragma unroll
        for (int k = 0; k < PC; k++) {
            s += psum_p[(size_t)(g * PC + k) * H4 + t];
            m = fmaxf(m, pmax_p[(size_t)(g * PC + k) * H4 + t]);
        }
        int cnt = gstart[g + 1] - gstart[g];
        p0_l[t] = s / fmaxf((float)cnt, 1.f);
        p0_l[H4 + t] = (cnt > 0) ? m : 0.f;
    }
    __syncthreads();

    {
        int j = t & 127, h = t >> 7;
        float acc = 0.f;
        int k0 = h * 256;
        for (int k = 0; k < 256; k++) acc += p0_l[k0 + k] * W1[(k0 + k) * H2 + j];
        p1part[h][j] = acc;
    }
    __syncthreads();
    if (t < H2) p1_l[t] = fmaxf(p1part[0][t] + p1part[1][t] + b1[t], 0.f);
    __syncthreads();

    {
        int c = t & 63, h = t >> 6;
        float acc = 0.f;
        int k0 = h * 32;
        for (int k = 0; k < 32; k++) acc += p1_l[k0 + k] * W2[(k0 + k) * H + c];
        p2part[h][c] = acc;
    }
    __syncthreads();
    if (t < H) p2_l[t] = fmaxf(((p2part[0][t] + p2part[1][t]) + (p2part[2][t] + p2part[3][t])) + b2[t], 0.f);
    __syncthreads();

    if (t < 64) {
        float v = p2_l[t] * Wo[t];
#pragma unroll
        for (int off = 32; off >= 1; off >>= 1) v += __shfl_xor(v, off, 64);
        if (t == 0) out[g] = v + bo[0];
    }
}

extern "C" void kernel_launch(void* const* d_in, const int* in_sizes, int n_in,
                              void* d_out, int out_size, void* d_ws, size_t ws_size,
                              hipStream_t stream) {
    const float* x       = (const float*)d_in[0];
    const int*   ei      = (const int*)d_in[1];
    const int*   batch   = (const int*)d_in[2];
    const float* conv1_W = (const float*)d_in[3];
    const float* conv1_b = (const float*)d_in[4];
    const float* bn1_g   = (const float*)d_in[5];
    const float* bn1_b   = (const float*)d_in[6];
    const float* ln_g    = (const float*)d_in[7];
    const float* ln_b    = (const float*)d_in[8];
    const float* prelu_a = (const float*)d_in[9];
    const float* gen_t   = (const float*)d_in[10];
    const float* mlp_W1  = (const float*)d_in[11];
    const float* mlp_b1  = (const float*)d_in[12];
    const float* mlp_bng = (const float*)d_in[13];
    const float* mlp_bnb = (const float*)d_in[14];
    const float* mlp_W2  = (const float*)d_in[15];
    const float* mlp_b2  = (const float*)d_in[16];
    const float* lin1_W  = (const float*)d_in[17];
    const float* lin1_b  = (const float*)d_in[18];
    const float* lin2_W  = (const float*)d_in[19];
    const float* lin2_b  = (const float*)d_in[20];
    const float* out_W   = (const float*)d_in[21];
    const float* out_b   = (const float*)d_in[22];
    float* out = (float*)d_out;

    float* ws   = (float*)d_ws;
    float* xc   = ws;                          // NND*H4
    float* u    = xc + (size_t)NND * H4;       // NND*H
    float* ua   = u + (size_t)NND * H;         // NND*H (t0 aliases)
    float* t0   = ua;
    float* dinv = ua + (size_t)NND * H;        // NND
    int* rowptr = (int*)(dinv + NND);          // NND+1
    int* next   = rowptr + (NND + 1);          // NND
    int* counts = next + NND;                  // NND
    int* bsum   = counts + NND;                // NB
    int* boff   = bsum + NB;                   // NB
    int* csr    = boff + NB;                   // NE
    float* psum_p = (float*)(csr + NE);        // NG*PC*H4
    float* pmax_p = psum_p + (size_t)NG * PC * H4;
    int* gstart = (int*)(pmax_p + (size_t)NG * PC * H4);  // NG+1
    uintptr_t wb = (uintptr_t)(gstart + NG + 1);
    wb = (wb + 15) & ~(uintptr_t)15;
    _Float16* w1f = (_Float16*)wb;             // 3*8192 halves
    _Float16* w2f = w1f + 3 * 8192;            // 3*8192 halves

    const int B = 256;
    const int gN   = (NND + B - 1) / B;
    const int gNH  = (NND * H) / B;
    const int gMLP = (NND + MT - 1) / MT;   // 782
    const int gEP  = NXP * ECH;

    // ---- CSR build + weight swizzle ----
    k_zero_counts<<<gN, B, 0, stream>>>(counts);
    k_count_p<<<gEP, B, 0, stream>>>(ei, counts);
    k_scan1<<<NB, B, 0, stream>>>(counts, rowptr, bsum);
    k_scan2<<<1, B, 0, stream>>>(bsum, boff, rowptr);
    k_scan3<<<NB, B, 0, stream>>>(boff, counts, rowptr, next, dinv);
    k_scatter_p<<<gEP, B, 0, stream>>>(ei, next, csr);
    k_gbounds<<<2, 256, 0, stream>>>(batch, gstart);
    k_wswz<<<12, 256, 0, stream>>>(mlp_W1, mlp_W2, w1f, w2f);

    // ---- GCNConv + LN0/PReLU0 ----
    k_conv1<<<gNH, B, 0, stream>>>(x, conv1_W, t0);
    k_gcn<<<gNH, B, 0, stream>>>(rowptr, csr, t0, dinv, conv1_b, bn1_g, bn1_b,
                                 ln_g, ln_b, prelu_a, xc, u);

    // ---- DeepGCN layers ----
    for (int i = 0; i < 3; i++) {
        k_gen<<<gNH, B, 0, stream>>>(rowptr, csr, u, gen_t, i, ua);
        int do_ln = (i < 2) ? 1 : 0;
        k_mlp<<<gMLP, B, 0, stream>>>(ua,
                                      w1f + (size_t)i * 8192, w2f + (size_t)i * 8192,
                                      mlp_b1 + i * H2,
                                      mlp_bng + i * H2, mlp_bnb + i * H2,
                                      mlp_b2 + i * H,
                                      xc, i,
                                      ln_g + (i + 1) * H, ln_b + (i + 1) * H,
                                      prelu_a + (i + 1) * H, u, do_ln);
    }

    // ---- pooling + readout ----
    k_pool1<<<NG * PC, B, 0, stream>>>(xc, gstart, psum_p, pmax_p);
    k_readout<<<NG, B, 0, stream>>>(psum_p, pmax_p, gstart,
                                    lin1_W, lin1_b, lin2_W, lin2_b, out_W, out_b, out);
}